// Round 11
// baseline (49156.586 us; speedup 1.0000x reference)
//
#include <hip/hip_runtime.h>
#include <math.h>

// Problem constants (match reference)
#define BB   256   // batch
#define TT   64    // timesteps
#define SS   256   // encoder seq len
#define VV   512   // vocab
#define EE   512   // embed dim
#define HH   1024  // hidden
#define ENCE 1024  // encoder dim
#define SUME 2048  // summary dim
#define NSP  4     // attention S-splits

typedef __attribute__((ext_vector_type(8))) _Float16 h8v;  // 8 fp16 (4 VGPR)
typedef __attribute__((ext_vector_type(4))) float f4v;

// fp32 -> fp16 (hi, lo*2^12) split. x ~= h + l * 2^-12, |err| <= 2^-24 |x|.
__device__ __forceinline__ void split16(float x, _Float16& h, _Float16& l) {
    h = (_Float16)x;
    l = (_Float16)((x - (float)h) * 4096.0f);
}
__device__ __forceinline__ float sigm(float x) { return 1.f / (1.f + expf(-x)); }

// Fused-epilogue descriptor for gemm_f16.
// type: 0 none, 1 tanh(+splits), 2 LSTM gate, 3 argmax+logits
struct Ep {
    int type, cw, target, t;
    int* counter;
    const float* bias;   // b (tanh), bih (gate), bout (argmax)
    const float* bias2;  // bhh (gate)
    float* dst;          // fp32 out (tanh opt), tokens (argmax)
    float* dst2;         // c state (gate), logits (argmax)
    _Float16 *dh, *dl;   // splits of tanh-out / h
    _Float16 *ch, *cl;   // splits of c (gate, optional)
};

// ===========================================================================
// LEGACY fp32 path (known-good): decoder_init always; full fallback if ws
// too small.
// ===========================================================================
__global__ __launch_bounds__(256) void gemm2(
    const float* __restrict__ A0, const float* __restrict__ W0, const int K0,
    const int lda0, const int ldw0,
    const float* __restrict__ A1, const float* __restrict__ W1, const int Ktot,
    const int lda1, const int ldw1,
    const float* __restrict__ b0, const float* __restrict__ b1,
    float* __restrict__ C, const int ldc, const int act)
{
    __shared__ float As[16][68];
    __shared__ float Ws[16][68];

    const int tid = threadIdx.x;
    const int n0  = blockIdx.x * 64;
    const int m0  = blockIdx.y * 64;
    const int lr  = tid >> 2;
    const int lc  = (tid & 3) << 2;
    const int tx  = tid & 15;
    const int ty  = tid >> 4;

    float acc[4][4] = {{0.f}};

    for (int k0 = 0; k0 < Ktot; k0 += 16) {
        const float* A; const float* W; int lda, ldw, kk;
        if (k0 < K0) { A = A0; W = W0; lda = lda0; ldw = ldw0; kk = k0; }
        else         { A = A1; W = W1; lda = lda1; ldw = ldw1; kk = k0 - K0; }

        const float4 av = *(const float4*)(A + (size_t)(m0 + lr) * lda + kk + lc);
        const float4 wv = *(const float4*)(W + (size_t)(n0 + lr) * ldw + kk + lc);

        __syncthreads();
        As[lc + 0][lr] = av.x; As[lc + 1][lr] = av.y;
        As[lc + 2][lr] = av.z; As[lc + 3][lr] = av.w;
        Ws[lc + 0][lr] = wv.x; Ws[lc + 1][lr] = wv.y;
        Ws[lc + 2][lr] = wv.z; Ws[lc + 3][lr] = wv.w;
        __syncthreads();

        #pragma unroll
        for (int p = 0; p < 16; ++p) {
            const float4 a4 = *(const float4*)&As[p][ty * 4];
            const float4 w4 = *(const float4*)&Ws[p][tx * 4];
            acc[0][0] += a4.x * w4.x; acc[0][1] += a4.x * w4.y;
            acc[0][2] += a4.x * w4.z; acc[0][3] += a4.x * w4.w;
            acc[1][0] += a4.y * w4.x; acc[1][1] += a4.y * w4.y;
            acc[1][2] += a4.y * w4.z; acc[1][3] += a4.y * w4.w;
            acc[2][0] += a4.z * w4.x; acc[2][1] += a4.z * w4.y;
            acc[2][2] += a4.z * w4.z; acc[2][3] += a4.z * w4.w;
            acc[3][0] += a4.w * w4.x; acc[3][1] += a4.w * w4.y;
            acc[3][2] += a4.w * w4.z; acc[3][3] += a4.w * w4.w;
        }
    }

    float bias[4];
    #pragma unroll
    for (int j = 0; j < 4; ++j) {
        const int n = n0 + tx * 4 + j;
        bias[j] = b0[n] + (b1 ? b1[n] : 0.f);
    }
    #pragma unroll
    for (int i = 0; i < 4; ++i) {
        const int m = m0 + ty * 4 + i;
        #pragma unroll
        for (int j = 0; j < 4; ++j) {
            float v = acc[i][j] + bias[j];
            if (act) v = tanhf(v);
            C[(size_t)m * ldc + n0 + tx * 4 + j] = v;
        }
    }
}

__global__ void lstm_gate(const float* __restrict__ g,
                          float* __restrict__ h, float* __restrict__ c)
{
    const int i = blockIdx.x * blockDim.x + threadIdx.x;
    if (i >= BB * HH) return;
    const int b = i / HH, k = i % HH;
    const float* gb = g + (size_t)b * 4 * HH;
    const float gi = gb[k];
    const float gf = gb[HH + k];
    const float gg = gb[2 * HH + k];
    const float go = gb[3 * HH + k];
    const float si = sigm(gi);
    const float sf = sigm(gf);
    const float so = sigm(go);
    const float cn = sf * c[i] + si * tanhf(gg);
    c[i] = cn;
    h[i] = so * tanhf(cn);
}

// Legacy two-pass fp32 attention (fallback path only).
__global__ __launch_bounds__(256) void attn_kernel(
    const float* __restrict__ q, const float* __restrict__ enc,
    float* __restrict__ cross)
{
    const int b = blockIdx.x, tid = threadIdx.x;
    __shared__ float qs[ENCE];
    __shared__ float sc[SS];
    __shared__ float red[256];

    const float* qb = q + (size_t)b * ENCE;
    const float* eb = enc + (size_t)b * SS * ENCE;

    for (int e = tid; e < ENCE; e += 256) qs[e] = qb[e];
    __syncthreads();

    {
        const float* row = eb + (size_t)tid * ENCE;
        float a = 0.f;
        for (int e = 0; e < ENCE; e += 4) {
            const float4 ev = *(const float4*)&row[e];
            a += ev.x * qs[e] + ev.y * qs[e + 1] + ev.z * qs[e + 2] + ev.w * qs[e + 3];
        }
        sc[tid] = a;
    }
    __syncthreads();

    red[tid] = sc[tid];
    __syncthreads();
    for (int off = 128; off > 0; off >>= 1) {
        if (tid < off) red[tid] = fmaxf(red[tid], red[tid + off]);
        __syncthreads();
    }
    const float mx = red[0];
    __syncthreads();
    const float ex = expf(sc[tid] - mx);
    red[tid] = ex;
    __syncthreads();
    for (int off = 128; off > 0; off >>= 1) {
        if (tid < off) red[tid] += red[tid + off];
        __syncthreads();
    }
    const float inv = 1.f / red[0];
    __syncthreads();
    sc[tid] = ex * inv;
    __syncthreads();

    float4 acc = {0.f, 0.f, 0.f, 0.f};
    const int e0 = tid * 4;
    for (int s = 0; s < SS; ++s) {
        const float w = sc[s];
        const float4 ev = *(const float4*)&eb[(size_t)s * ENCE + e0];
        acc.x += w * ev.x; acc.y += w * ev.y; acc.z += w * ev.z; acc.w += w * ev.w;
    }
    *(float4*)&cross[(size_t)b * ENCE + e0] = acc;
}

// ---------------------------------------------------------------------------
// Split-flash attention with FUSED combine: grid (NSP=4, BB). Block (sp,b)
// handles s-rows [sp*64, sp*64+64) in 8-row LDS chunks; last block per b
// combines the NSP partials -> cross fp16 splits.
// ---------------------------------------------------------------------------
__global__ __launch_bounds__(256) void attn_part_k(
    const float* __restrict__ q, const float* __restrict__ enc,
    float* __restrict__ po, float* __restrict__ pm, float* __restrict__ pl,
    int* __restrict__ actr,
    _Float16* __restrict__ crh, _Float16* __restrict__ crl)
{
    const int sp = blockIdx.x, b = blockIdx.y, tid = threadIdx.x;
    __shared__ float qs[ENCE];
    __shared__ float es[8 * ENCE];   // 32 KB
    __shared__ float sc[8];
    __shared__ int lastf;

    const float* qb = q + (size_t)b * ENCE;
    const float* eb = enc + (size_t)b * SS * ENCE + (size_t)sp * 64 * ENCE;

    *(float4*)&qs[tid * 4] = *(const float4*)&qb[tid * 4];
    __syncthreads();

    const int sl  = tid >> 5;    // 0..7 : row for score phase
    const int seg = tid & 31;    // 0..31: column group
    const int e0  = tid * 4;

    float m = -INFINITY, l = 0.f;
    float4 o = {0.f, 0.f, 0.f, 0.f};

    for (int ch = 0; ch < 8; ++ch) {
        {   // stage 8 rows, fully coalesced
            const float* src = eb + (size_t)ch * 8 * ENCE;
            #pragma unroll
            for (int i = 0; i < 8; ++i) {
                const int idx = tid * 4 + i * 1024;
                *(float4*)&es[idx] = *(const float4*)&src[idx];
            }
        }
        __syncthreads();

        {   // scores: 32 threads per row
            float a = 0.f;
            const float* row = &es[sl * ENCE];
            #pragma unroll
            for (int j = 0; j < 8; ++j) {
                const int e = seg * 4 + j * 128;
                const float4 ev = *(const float4*)&row[e];
                const float4 qv = *(const float4*)&qs[e];
                a += ev.x * qv.x + ev.y * qv.y + ev.z * qv.z + ev.w * qv.w;
            }
            a += __shfl_xor(a, 1, 32);
            a += __shfl_xor(a, 2, 32);
            a += __shfl_xor(a, 4, 32);
            a += __shfl_xor(a, 8, 32);
            a += __shfl_xor(a, 16, 32);
            if (seg == 0) sc[sl] = a;
        }
        __syncthreads();

        {   // online softmax update (block-uniform m, l)
            float cm = sc[0];
            #pragma unroll
            for (int i = 1; i < 8; ++i) cm = fmaxf(cm, sc[i]);
            const float mn = fmaxf(m, cm);
            const float scale = expf(m - mn);
            o.x *= scale; o.y *= scale; o.z *= scale; o.w *= scale;
            l *= scale;
            float p[8];
            #pragma unroll
            for (int i = 0; i < 8; ++i) { p[i] = expf(sc[i] - mn); l += p[i]; }
            #pragma unroll
            for (int i = 0; i < 8; ++i) {
                const float4 ev = *(const float4*)&es[i * ENCE + e0];
                o.x += p[i] * ev.x; o.y += p[i] * ev.y;
                o.z += p[i] * ev.z; o.w += p[i] * ev.w;
            }
            m = mn;
        }
        __syncthreads();
    }

    *(float4*)&po[((size_t)sp * BB + b) * ENCE + e0] = o;
    if (tid == 0) { pm[sp * BB + b] = m; pl[sp * BB + b] = l; }

    // ---- fused combine: last block per b ----
    __threadfence();
    __syncthreads();
    if (tid == 0) lastf = (atomicAdd(&actr[b], 1) == NSP - 1);
    __syncthreads();
    if (!lastf) return;
    __threadfence();

    float ms = -INFINITY;
    #pragma unroll
    for (int p = 0; p < NSP; ++p) ms = fmaxf(ms, pm[p * BB + b]);
    float w[NSP]; float L = 0.f;
    #pragma unroll
    for (int p = 0; p < NSP; ++p) {
        w[p] = expf(pm[p * BB + b] - ms);
        L += pl[p * BB + b] * w[p];
    }
    const float inv = 1.f / L;

    float4 acc = {0.f, 0.f, 0.f, 0.f};
    #pragma unroll
    for (int p = 0; p < NSP; ++p) {
        const float4 v = *(const float4*)&po[((size_t)p * BB + b) * ENCE + e0];
        acc.x += w[p] * v.x; acc.y += w[p] * v.y;
        acc.z += w[p] * v.z; acc.w += w[p] * v.w;
    }
    const float4 r = {acc.x * inv, acc.y * inv, acc.z * inv, acc.w * inv};

    _Float16 h4[4], l4[4];
    split16(r.x, h4[0], l4[0]); split16(r.y, h4[1], l4[1]);
    split16(r.z, h4[2], l4[2]); split16(r.w, h4[3], l4[3]);
    *(uint2*)&crh[(size_t)b * ENCE + e0] = *(uint2*)h4;
    *(uint2*)&crl[(size_t)b * ENCE + e0] = *(uint2*)l4;

    __syncthreads();
    if (tid == 0) actr[b] = 0;
}

// Legacy fallback out projection (fallback path only).
__global__ __launch_bounds__(256) void out_kernel(
    const float* __restrict__ lin, const float* __restrict__ Wout,
    const float* __restrict__ bout, float* __restrict__ tokens,
    float* __restrict__ logits, const int t)
{
    const int b = blockIdx.x, tid = threadIdx.x;
    __shared__ float ls[HH];
    __shared__ float vmax[256];
    __shared__ int   vidx[256];

    const float* lb = lin + (size_t)b * HH;
    for (int e = tid; e < HH; e += 256) ls[e] = lb[e];
    __syncthreads();

    float best = -INFINITY; int bi = 0;
    for (int n = tid; n < VV; n += 256) {
        const float* wr = Wout + (size_t)n * HH;
        float a = bout[n];
        for (int e = 0; e < HH; e += 4) {
            const float4 wv = *(const float4*)&wr[e];
            a += wv.x * ls[e] + wv.y * ls[e + 1] + wv.z * ls[e + 2] + wv.w * ls[e + 3];
        }
        logits[((size_t)b * TT + t) * VV + n] = a;
        if (a > best) { best = a; bi = n; }
    }
    vmax[tid] = best; vidx[tid] = bi;
    __syncthreads();
    for (int off = 128; off > 0; off >>= 1) {
        if (tid < off) {
            const float vo = vmax[tid + off]; const int io = vidx[tid + off];
            if (vo > vmax[tid] || (vo == vmax[tid] && io < vidx[tid])) {
                vmax[tid] = vo; vidx[tid] = io;
            }
        }
        __syncthreads();
    }
    if (tid == 0) tokens[(size_t)b * TT + t] = (float)vidx[0];
}

__global__ void gather_emb(const int* __restrict__ y,
                           const float* __restrict__ table,
                           float* __restrict__ emb, const int t)
{
    const int i = blockIdx.x * blockDim.x + threadIdx.x;
    if (i >= BB * EE) return;
    const int b = i / EE, e = i % EE;
    emb[i] = table[(size_t)y[(size_t)b * TT + t] * EE + e];
}

// init scatter + optional fp16 splits for h0, h1, c1 (parity-0 buffers)
__global__ void scatter_init_s(const float* __restrict__ ini,
                               float* __restrict__ h0, float* __restrict__ h1,
                               float* __restrict__ c0, float* __restrict__ c1,
                               _Float16* __restrict__ h0h, _Float16* __restrict__ h0l,
                               _Float16* __restrict__ h1h, _Float16* __restrict__ h1l,
                               _Float16* __restrict__ c1h, _Float16* __restrict__ c1l)
{
    const int i = blockIdx.x * blockDim.x + threadIdx.x;
    if (i >= BB * 4 * HH) return;
    const int b = i / (4 * HH), j = i % (4 * HH);
    const int i1 = j / (2 * HH);
    const int rem = j % (2 * HH);
    const int i2 = rem / HH;
    const int k = rem % HH;
    const float v = ini[i];
    const size_t o = (size_t)b * HH + k;
    float* dst = (i1 == 0) ? (i2 == 0 ? h0 : h1) : (i2 == 0 ? c0 : c1);
    dst[o] = v;
    if (h0h) {
        if (i1 == 0) {
            _Float16 h, l; split16(v, h, l);
            if (i2 == 0) { h0h[o] = h; h0l[o] = l; }
            else         { h1h[o] = h; h1l[o] = l; }
        } else if (i2 == 1) {
            _Float16 h, l; split16(v, h, l);
            c1h[o] = h; c1l[o] = l;
        }
    }
}

__global__ void zero_kernel(float* __restrict__ p, const int n)
{
    const int i = blockIdx.x * blockDim.x + threadIdx.x;
    if (i < n) p[i] = 0.f;
}

// ===========================================================================
// fp16 2-split MFMA path: 3 passes, 2 accumulators, fp32-grade (~2^-24).
// ===========================================================================

// fp32 weights -> fp16 (hi, lo*2^12), packed into column slice of [N][dld].
__global__ void conv_w2(const float* __restrict__ src, const int N, const int K,
                        _Float16* __restrict__ dh, _Float16* __restrict__ dl,
                        const int dld, const int coff)
{
    const int total = N * K;
    for (int i = blockIdx.x * blockDim.x + threadIdx.x; i < total;
         i += gridDim.x * blockDim.x) {
        const int n = i / K, k = i - n * K;
        const size_t o = (size_t)n * dld + coff + k;
        split16(src[i], dh[o], dl[o]);
    }
}

// ---------------------------------------------------------------------------
// gemm_f16: 64x128 tile, 4 waves (2m x 2n), BK=32, split-fp16 3-pass,
// software-pipelined, split-K partials, FUSED epilogue via last-block
// counter (Ep). Grid: (N/128, BB/64, P), 256 threads, chunk = Kt/P.
// If rawA0 != null: A0-side reads fp32 rows of rawA0 at row yidx[m*TT+t]
// (fused embedding gather), split in-registers.
// ---------------------------------------------------------------------------
__global__ __launch_bounds__(256) void gemm_f16(
    const _Float16* __restrict__ A0h, const _Float16* __restrict__ A0l, const int lda0,
    const _Float16* __restrict__ A1h, const _Float16* __restrict__ A1l, const int lda1,
    const int K0,
    const float* __restrict__ rawA0, const int* __restrict__ yidx,
    const _Float16* __restrict__ Wh, const _Float16* __restrict__ Wl,
    const int Kt, float* __restrict__ Cpart, const int N, const int chunk,
    const Ep E)
{
    __shared__ _Float16 Ash[64][40], Asl[64][40];
    __shared__ _Float16 Wsh[128][40], Wsl[128][40];
    __shared__ int lastflag;

    const int tid = threadIdx.x;
    const int n0 = blockIdx.x * 128;
    const int m0 = blockIdx.y * 64;
    const int p  = blockIdx.z;
    const int kbeg = p * chunk, kend = kbeg + chunk;

    const int lane = tid & 63, wave = tid >> 6;
    const int wm = wave >> 1, wn = wave & 1;
    const int l15 = lane & 15, lg = lane >> 4;

    const int ar = tid >> 2, ag = tid & 3;     // staging: row 0..63, k-grp 0..3

    const float* Araw = rawA0
        ? rawA0 + (size_t)yidx[(size_t)(m0 + ar) * TT + E.t] * lda0 : nullptr;

    f4v accm[2][4], accc[2][4];
    #pragma unroll
    for (int i = 0; i < 2; ++i)
        #pragma unroll
        for (int j = 0; j < 4; ++j) {
            accm[i][j] = (f4v){0.f, 0.f, 0.f, 0.f};
            accc[i][j] = (f4v){0.f, 0.f, 0.f, 0.f};
        }

    uint4 avh, avl, wh0, wl0, wh1, wl1;

    auto load_tile = [&](int kk_) {
        const int col = kk_ + ag * 8;
        if (col < K0) {
            if (Araw) {
                const float4 f0 = *(const float4*)(Araw + col);
                const float4 f1 = *(const float4*)(Araw + col + 4);
                const float xs[8] = {f0.x, f0.y, f0.z, f0.w, f1.x, f1.y, f1.z, f1.w};
                h8v vh, vl;
                #pragma unroll
                for (int j = 0; j < 8; ++j) {
                    _Float16 th, tl;
                    split16(xs[j], th, tl);
                    vh[j] = th;
                    vl[j] = tl;
                }
                avh = *(uint4*)&vh; avl = *(uint4*)&vl;
            } else {
                const size_t o = (size_t)(m0 + ar) * lda0 + col;
                avh = *(const uint4*)(A0h + o);
                avl = *(const uint4*)(A0l + o);
            }
        } else {
            const size_t o = (size_t)(m0 + ar) * lda1 + (col - K0);
            avh = *(const uint4*)(A1h + o);
            avl = *(const uint4*)(A1l + o);
        }
        const size_t o0 = (size_t)(n0 + ar) * Kt + kk_ + ag * 8;
        const size_t o1 = o0 + (size_t)64 * Kt;
        wh0 = *(const uint4*)(Wh + o0);
        wl0 = *(const uint4*)(Wl + o0);
        wh1 = *(const uint4*)(Wh + o1);
        wl1 = *(const uint4*)(Wl + o1);
    };

    load_tile(kbeg);

    for (int kk = kbeg; kk < kend; kk += 32) {
        __syncthreads();

        *(uint4*)&Ash[ar][ag * 8] = avh;
        *(uint4*)&Asl[ar][ag * 8] = avl;
        *(uint4*)&Wsh[ar][ag * 8] = wh0;
        *(uint4*)&Wsl[ar][ag * 8] = wl0;
        *(uint4*)&Wsh[64 + ar][ag * 8] = wh1;
        *(uint4*)&Wsl[64 + ar][ag * 8] = wl1;

        __syncthreads();

        if (kk + 32 < kend) load_tile(kk + 32);   // in flight under compute

        h8v afh[2], afl[2];
        #pragma unroll
        for (int fr = 0; fr < 2; ++fr) {
            const int r = wm * 32 + fr * 16 + l15;
            afh[fr] = *(const h8v*)&Ash[r][lg * 8];
            afl[fr] = *(const h8v*)&Asl[r][lg * 8];
        }
        #pragma unroll
        for (int fn = 0; fn < 4; ++fn) {
            const int r = wn * 64 + fn * 16 + l15;
            const h8v wfh = *(const h8v*)&Wsh[r][lg * 8];
            const h8v wfl = *(const h8v*)&Wsl[r][lg * 8];
            #pragma unroll
            for (int fr = 0; fr < 2; ++fr) {
                accm[fr][fn] = __builtin_amdgcn_mfma_f32_16x16x32_f16(
                    afh[fr], wfh, accm[fr][fn], 0, 0, 0);
                accc[fr][fn] = __builtin_amdgcn_mfma_f32_16x16x32_f16(
                    afh[fr], wfl, accc[fr][fn], 0, 0, 0);
                accc[fr][fn] = __builtin_amdgcn_mfma_f32_16x16x32_f16(
                    afl[fr], wfh, accc[fr][fn], 0, 0, 0);
            }
        }
    }

    // ---- write split-K partials ----
    const float s12 = 0.000244140625f;  // 2^-12
    float* slab = Cpart + (size_t)p * BB * N;
    #pragma unroll
    for (int fr = 0; fr < 2; ++fr) {
        const int row0 = m0 + wm * 32 + fr * 16 + lg * 4;
        #pragma unroll
        for (int fn = 0; fn < 4; ++fn) {
            const int col = n0 + wn * 64 + fn * 16 + l15;
            #pragma unroll
            for (int j = 0; j < 4; ++j)
                slab[(size_t)(row0 + j) * N + col] =
                    accm[fr][fn][j] + s12 * accc[fr][fn][j];
        }
    }

    // ---- fused epilogue: last block of counter group reduces ----
    if (E.type == 0) return;
    const int cidx = blockIdx.y * E.cw + (blockIdx.x % E.cw);
    __threadfence();
    __syncthreads();
    if (tid == 0) lastflag = (atomicAdd(E.counter + cidx, 1) == E.target - 1);
    __syncthreads();
    if (!lastflag) return;
    __threadfence();

    const int P = gridDim.z;
    const int b0 = m0;

    if (E.type == 1) {
        // tanh + optional fp32 dst + optional fp16 splits, over 64x128 tile
        for (int idx = tid; idx < 64 * 32; idx += 256) {
            const int b = b0 + (idx >> 5);
            const int n = n0 + (idx & 31) * 4;
            float4 s = *(const float4*)&E.bias[n];
            for (int pp = 0; pp < P; ++pp) {
                const float4 v = *(const float4*)&Cpart[
                    (size_t)pp * BB * N + (size_t)b * N + n];
                s.x += v.x; s.y += v.y; s.z += v.z; s.w += v.w;
            }
            s.x = tanhf(s.x); s.y = tanhf(s.y); s.z = tanhf(s.z); s.w = tanhf(s.w);
            if (E.dst) *(float4*)&E.dst[(size_t)b * N + n] = s;
            if (E.dh) {
                _Float16 h4[4], l4[4];
                split16(s.x, h4[0], l4[0]); split16(s.y, h4[1], l4[1]);
                split16(s.z, h4[2], l4[2]); split16(s.w, h4[3], l4[3]);
                *(uint2*)&E.dh[(size_t)b * N + n] = *(uint2*)h4;
                *(uint2*)&E.dl[(size_t)b * N + n] = *(uint2*)l4;
            }
        }
    } else if (E.type == 2) {
        // LSTM gate over 64 rows x 128 k-cols (group of 4 x-tiles)
        const int kb = blockIdx.x % E.cw;
        for (int idx = tid; idx < 64 * 32; idx += 256) {
            const int b = b0 + (idx >> 5);
            const int k = kb * 128 + (idx & 31) * 4;
            float4 gi = *(const float4*)&E.bias[k];
            float4 gf = *(const float4*)&E.bias[HH + k];
            float4 gg = *(const float4*)&E.bias[2 * HH + k];
            float4 go = *(const float4*)&E.bias[3 * HH + k];
            {
                float4 v;
                v = *(const float4*)&E.bias2[k];
                gi.x += v.x; gi.y += v.y; gi.z += v.z; gi.w += v.w;
                v = *(const float4*)&E.bias2[HH + k];
                gf.x += v.x; gf.y += v.y; gf.z += v.z; gf.w += v.w;
                v = *(const float4*)&E.bias2[2 * HH + k];
                gg.x += v.x; gg.y += v.y; gg.z += v.z; gg.w += v.w;
                v = *(const float4*)&E.bias2[3 * HH + k];
                go.x += v.x; go.y += v.y; go.z += v.z; go.w += v.w;
            }
            for (int pp = 0; pp < P; ++pp) {
                const float* base = Cpart + (size_t)pp * BB * N + (size_t)b * N;
                float4 v;
                v = *(const float4*)&base[k];
                gi.x += v.x; gi.y += v.y; gi.z += v.z; gi.w += v.w;
                v = *(const float4*)&base[HH + k];
                gf.x += v.x; gf.y += v.y; gf.z += v.z; gf.w += v.w;
                v = *(const float4*)&base[2 * HH + k];
                gg.x += v.x; gg.y += v.y; gg.z += v.z; gg.w += v.w;
                v = *(const float4*)&base[3 * HH + k];
                go.x += v.x; go.y += v.y; go.z += v.z; go.w += v.w;
            }
            const size_t o = (size_t)b * HH + k;
            const float4 cold = *(const float4*)&E.dst2[o];
            float4 cn, hn;
            cn.x = sigm(gf.x) * cold.x + sigm(gi.x) * tanhf(gg.x);
            cn.y = sigm(gf.y) * cold.y + sigm(gi.y) * tanhf(gg.y);
            cn.z = sigm(gf.z) * cold.z + sigm(gi.z) * tanhf(gg.z);
            cn.w = sigm(gf.w) * cold.w + sigm(gi.w) * tanhf(gg.w);
            hn.x = sigm(go.x) * tanhf(cn.x);
            hn.y = sigm(go.y) * tanhf(cn.y);
            hn.z = sigm(go.z) * tanhf(cn.z);
            hn.w = sigm(go.w) * tanhf(cn.w);
            *(float4*)&E.dst2[o] = cn;
            _Float16 h4[4], l4[4];
            split16(hn.x, h4[0], l4[0]); split16(hn.y, h4[1], l4[1]);
            split16(hn.z, h4[2], l4[2]); split16(hn.w, h4[3], l4[3]);
            *(uint2*)&E.dh[o] = *(uint2*)h4;
            *(uint2*)&E.dl[o] = *(uint2*)l4;
            if (E.ch) {
                split16(cn.x, h4[0], l4[0]); split16(cn.y, h4[1], l4[1]);
                split16(cn.z, h4[2], l4[2]); split16(cn.w, h4[3], l4[3]);
                *(uint2*)&E.ch[o] = *(uint2*)h4;
                *(uint2*)&E.cl[o] = *(uint2*)l4;
            }
        }
    } else {
        // argmax + logits over 64 rows x all VV cols (counter per y)
        float* amax = (float*)&Ash[0][0];
        int*   aidx = (int*)&Asl[0][0];
        const int r = tid & 63;
        const int ppart = tid >> 6;       // 0..3, cols ppart*128..+127
        const int b = b0 + r;
        float best = -INFINITY; int bi = 0;
        for (int c4 = 0; c4 < 32; ++c4) {
            const int n = ppart * 128 + c4 * 4;
            float4 s = *(const float4*)&E.bias[n];
            for (int pp = 0; pp < P; ++pp) {
                const float4 v = *(const float4*)&Cpart[
                    (size_t)pp * BB * N + (size_t)b * N + n];
                s.x += v.x; s.y += v.y; s.z += v.z; s.w += v.w;
            }
            *(float4*)&E.dst2[((size_t)b * TT + E.t) * VV + n] = s;
            if (s.x > best) { best = s.x; bi = n; }
            if (s.y > best) { best = s.y; bi = n + 1; }
            if (s.z > best) { best = s.z; bi = n + 2; }
            if (s.w > best) { best = s.w; bi = n + 3; }
        }
        amax[tid] = best; aidx[tid] = bi;
        __syncthreads();
        if (tid < 64) {
            float bb = amax[tid]; int ii = aidx[tid];
            #pragma unroll
            for (int q = 1; q < 4; ++q) {
                const float v = amax[tid + q * 64]; const int jj = aidx[tid + q * 64];
                if (v > bb || (v == bb && jj < ii)) { bb = v; ii = jj; }
            }
            E.dst[(size_t)(b0 + tid) * TT + E.t] = (float)ii;
        }
    }

    __syncthreads();
    if (tid == 0) E.counter[cidx] = 0;
}

// ===========================================================================
extern "C" void kernel_launch(void* const* d_in, const int* in_sizes, int n_in,
                              void* d_out, int out_size, void* d_ws, size_t ws_size,
                              hipStream_t stream)
{
    const int*   y         = (const int*)  d_in[0];
    const float* enc       = (const float*)d_in[1];
    const float* esum      = (const float*)d_in[2];
    const float* emb_table = (const float*)d_in[3];
    const float* W_init    = (const float*)d_in[4];
    const float* b_init    = (const float*)d_in[5];
    const float* W_ci      = (const float*)d_in[6];
    const float* b_ci      = (const float*)d_in[7];
    const float* Wih0      = (const float*)d_in[8];
    const float* Whh0      = (const float*)d_in[9];
    const float* bih0      = (const float*)d_in[10];
    const float* bhh0      = (const float*)d_in[11];
    const float* Wih1      = (const float*)d_in[12];
    const float* Whh1      = (const float*)d_in[13];
    const float* bih1      = (const float*)d_in[14];
    const float* bhh1      = (const float*)d_in[15];
    const float* Wq        = (const float*)d_in[16];
    const float* bq        = (const float*)d_in[17];
    const float* Wco       = (const float*)d_in[18];
    const float* bco       = (const float*)d_in[19];
    const float* Wout      = (const float*)d_in[20];
    const float* bout      = (const float*)d_in[21];

    float* out    = (float*)d_out;
    float* tokens = out;
    float* logits = out + (size_t)BB * TT;

    // ---- workspace carve ----
    char* wsb = (char*)d_ws;
    size_t off = 0;
    auto alloc = [&](size_t bytes) -> char* {
        char* p = wsb + off;
        off = (off + bytes + 255) & ~(size_t)255;
        return p;
    };
    float* h0    = (float*)alloc((size_t)BB * HH * 4);
    float* h1    = (float*)alloc((size_t)BB * HH * 4);
    float* c0    = (float*)alloc((size_t)BB * HH * 4);
    float* c1    = (float*)alloc((size_t)BB * HH * 4);
    float* cross = (float*)alloc((size_t)BB * ENCE * 4);
    float* xbuf  = (float*)alloc((size_t)BB * EE * 4);
    float* embb  = (float*)alloc((size_t)BB * EE * 4);
    float* gbuf  = (float*)alloc((size_t)BB * 4 * HH * 4);
    float* qbuf  = (float*)alloc((size_t)BB * ENCE * 4);

    float* part = (float*)alloc((size_t)16 * BB * HH * 4);   // 16 MiB

    // fp16 weight splits, row-major [N][ld]
    _Float16 *ci_h, *ci_l, *g0_h, *g0_l, *g1_h, *g1_l, *wq_h, *wq_l,
             *wc_h, *wc_l, *wo_h, *wo_l;
    ci_h = (_Float16*)alloc((size_t)EE * 1536 * 2);
    ci_l = (_Float16*)alloc((size_t)EE * 1536 * 2);
    g0_h = (_Float16*)alloc((size_t)4 * HH * 1536 * 2);
    g0_l = (_Float16*)alloc((size_t)4 * HH * 1536 * 2);
    g1_h = (_Float16*)alloc((size_t)4 * HH * 2048 * 2);
    g1_l = (_Float16*)alloc((size_t)4 * HH * 2048 * 2);
    wq_h = (_Float16*)alloc((size_t)ENCE * 2048 * 2);
    wq_l = (_Float16*)alloc((size_t)ENCE * 2048 * 2);
    wc_h = (_Float16*)alloc((size_t)HH * 2048 * 2);
    wc_l = (_Float16*)alloc((size_t)HH * 2048 * 2);
    wo_h = (_Float16*)alloc((size_t)VV * HH * 2);
    wo_l = (_Float16*)alloc((size_t)VV * HH * 2);

    // fp16 activation splits (h0/h1 ping-pong: gate epilogue writes alias
    // the same GEMM's A-operand otherwise)
    _Float16* xbh  = (_Float16*)alloc((size_t)BB * EE * 2);
    _Float16* xbl  = (_Float16*)alloc((size_t)BB * EE * 2);
    _Float16* h0h2[2], *h0l2[2], *h1h2[2], *h1l2[2];
    for (int i = 0; i < 2; ++i) {
        h0h2[i] = (_Float16*)alloc((size_t)BB * HH * 2);
        h0l2[i] = (_Float16*)alloc((size_t)BB * HH * 2);
        h1h2[i] = (_Float16*)alloc((size_t)BB * HH * 2);
        h1l2[i] = (_Float16*)alloc((size_t)BB * HH * 2);
    }
    _Float16* c1h  = (_Float16*)alloc((size_t)BB * HH * 2);
    _Float16* c1l  = (_Float16*)alloc((size_t)BB * HH * 2);
    _Float16* crh  = (_Float16*)alloc((size_t)BB * ENCE * 2);
    _Float16* crl  = (_Float16*)alloc((size_t)BB * ENCE * 2);
    _Float16* lnh  = (_Float16*)alloc((size_t)BB * HH * 2);
    _Float16* lnl  = (_Float16*)alloc((size_t)BB * HH * 2);

    // attention partials + counters
    float* po = (float*)alloc((size_t)NSP * BB * ENCE * 4);
    float* pm = (float*)alloc((size_t)NSP * BB * 4);
    float* pl = (float*)alloc((size_t)NSP * BB * 4);
    int* gctr = (int*)alloc(256 * 4);
    int* actr = (int*)alloc(256 * 4);
    const size_t need_mfma = off;

    const int mfma_ok = (ws_size >= need_mfma);

    const dim3 thr(256);

    // ---- decoder_init (fp32, once) ----
    gemm2<<<dim3(4 * HH / 64, BB / 64), thr, 0, stream>>>(
        esum, W_init, SUME, SUME, SUME,
        nullptr, nullptr, SUME, 0, 0,
        b_init, nullptr, gbuf, 4 * HH, 1);
    scatter_init_s<<<dim3(BB * 4 * HH / 256), thr, 0, stream>>>(
        gbuf, h0, h1, c0, c1,
        mfma_ok ? h0h2[0] : nullptr, h0l2[0], h1h2[0], h1l2[0], c1h, c1l);
    zero_kernel<<<dim3(BB * ENCE / 256), thr, 0, stream>>>(cross, BB * ENCE);

    if (!mfma_ok) {
        for (int t = 0; t < TT; ++t) {
            gather_emb<<<dim3(BB * EE / 256), thr, 0, stream>>>(y, emb_table, embb, t);
            gemm2<<<dim3(EE / 64, BB / 64), thr, 0, stream>>>(
                embb, W_ci, EE, EE, EE + ENCE,
                cross, W_ci + EE, EE + ENCE, ENCE, EE + ENCE,
                b_ci, nullptr, xbuf, EE, 1);
            gemm2<<<dim3(4 * HH / 64, BB / 64), thr, 0, stream>>>(
                xbuf, Wih0, EE, EE, EE,
                h0, Whh0, EE + HH, HH, HH,
                bih0, bhh0, gbuf, 4 * HH, 0);
            lstm_gate<<<dim3(BB * HH / 256), thr, 0, stream>>>(gbuf, h0, c0);
            gemm2<<<dim3(4 * HH / 64, BB / 64), thr, 0, stream>>>(
                h0, Wih1, HH, HH, HH,
                h1, Whh1, 2 * HH, HH, HH,
                bih1, bhh1, gbuf, 4 * HH, 0);
            lstm_gate<<<dim3(BB * HH / 256), thr, 0, stream>>>(gbuf, h1, c1);
            gemm2<<<dim3(ENCE / 64, BB / 64), thr, 0, stream>>>(
                h1, Wq, HH, HH, 2 * HH,
                c1, Wq + HH, 2 * HH, HH, 2 * HH,
                bq, nullptr, qbuf, ENCE, 1);
            attn_kernel<<<dim3(BB), thr, 0, stream>>>(qbuf, enc, cross);
            gemm2<<<dim3(HH / 64, BB / 64), thr, 0, stream>>>(
                h1, Wco, HH, HH, ENCE + HH,
                cross, Wco + HH, ENCE + HH, ENCE, ENCE + HH,
                bco, nullptr, qbuf, HH, 1);
            out_kernel<<<dim3(BB), thr, 0, stream>>>(qbuf, Wout, bout, tokens, logits, t);
        }
        return;
    }

    // ---- one-time weight fp16-splits + counter zero ----
    const dim3 cg(4096);
    conv_w2<<<cg, thr, 0, stream>>>(W_ci, EE, EE + ENCE, ci_h, ci_l, 1536, 0);
    conv_w2<<<cg, thr, 0, stream>>>(Wih0, 4 * HH, EE, g0_h, g0_l, 1536, 0);
    conv_w2<<<cg, thr, 0, stream>>>(Whh0, 4 * HH, HH, g0_h, g0_l, 1536, EE);
    conv_w2<<<cg, thr, 0, stream>>>(Wih1, 4 * HH, HH, g1_h, g1_l, 2048, 0);
    conv_w2<<<cg, thr, 0, stream>>>(Whh1, 4 * HH, HH, g1_h, g1_l, 2048, HH);
    conv_w2<<<cg, thr, 0, stream>>>(Wq, ENCE, 2 * HH, wq_h, wq_l, 2048, 0);
    conv_w2<<<cg, thr, 0, stream>>>(Wco, HH, ENCE + HH, wc_h, wc_l, 2048, 0);
    conv_w2<<<cg, thr, 0, stream>>>(Wout, VV, HH, wo_h, wo_l, HH, 0);
    zero_kernel<<<dim3(BB * ENCE / 512), thr, 0, stream>>>((float*)crh, BB * ENCE / 2);
    zero_kernel<<<dim3(BB * ENCE / 512), thr, 0, stream>>>((float*)crl, BB * ENCE / 2);
    zero_kernel<<<dim3(2), thr, 0, stream>>>((float*)gctr, 512);  // gctr+actr

    for (int t = 0; t < TT; ++t) {
        const int hr = t & 1, hw = hr ^ 1;

        // x = tanh([emb_table[y[:,t]] | cross] @ Wci^T + b_ci)  (fused gather+ep)
        {
            Ep e{1, 4, 8, t, gctr, b_ci, nullptr, nullptr, nullptr,
                 xbh, xbl, nullptr, nullptr};
            gemm_f16<<<dim3(4, 4, 8), thr, 0, stream>>>(
                nullptr, nullptr, EE, crh, crl, ENCE, EE,
                emb_table, y, ci_h, ci_l, 1536, part, EE, 1536 / 8, e);
        }

        // layer0 gates (fused gate epilogue; h0 splits ping-pong)
        {
            Ep e{2, 8, 16, t, gctr, bih0, bhh0, nullptr, c0,
                 h0h2[hw], h0l2[hw], nullptr, nullptr};
            gemm_f16<<<dim3(32, 4, 4), thr, 0, stream>>>(
                xbh, xbl, EE, h0h2[hr], h0l2[hr], HH, EE,
                nullptr, nullptr, g0_h, g0_l, 1536, part, 4 * HH, 1536 / 4, e);
        }

        // layer1 gates (fused; h1 ping-pong; c1 splits single-buffer)
        {
            Ep e{2, 8, 16, t, gctr, bih1, bhh1, nullptr, c1,
                 h1h2[hw], h1l2[hw], c1h, c1l};
            gemm_f16<<<dim3(32, 4, 4), thr, 0, stream>>>(
                h0h2[hw], h0l2[hw], HH, h1h2[hr], h1l2[hr], HH, HH,
                nullptr, nullptr, g1_h, g1_l, 2048, part, 4 * HH, 2048 / 4, e);
        }

        // q = tanh([h1 | c1] @ Wq^T + bq) -> qbuf (fp32)
        {
            Ep e{1, 8, 8, t, gctr, bq, nullptr, qbuf, nullptr,
                 nullptr, nullptr, nullptr, nullptr};
            gemm_f16<<<dim3(8, 4, 8), thr, 0, stream>>>(
                h1h2[hw], h1l2[hw], HH, c1h, c1l, HH, HH,
                nullptr, nullptr, wq_h, wq_l, 2048, part, ENCE, 2048 / 8, e);
        }

        // attention: split-flash partials + fused combine -> cross splits
        attn_part_k<<<dim3(NSP, BB), thr, 0, stream>>>(
            qbuf, enc, po, pm, pl, actr, crh, crl);

        // lin = tanh([h1 | cross] @ Wco^T + bco) -> lnh/lnl
        {
            Ep e{1, 8, 8, t, gctr, bco, nullptr, nullptr, nullptr,
                 lnh, lnl, nullptr, nullptr};
            gemm_f16<<<dim3(8, 4, 8), thr, 0, stream>>>(
                h1h2[hw], h1l2[hw], HH, crh, crl, ENCE, HH,
                nullptr, nullptr, wc_h, wc_l, 2048, part, HH, 2048 / 8, e);
        }

        // logits GEMM + fused argmax epilogue
        {
            Ep e{3, 1, 32, t, gctr, bout, nullptr, tokens, logits,
                 nullptr, nullptr, nullptr, nullptr};
            gemm_f16<<<dim3(4, 4, 8), thr, 0, stream>>>(
                lnh, lnl, HH, nullptr, nullptr, HH, HH,
                nullptr, nullptr, wo_h, wo_l, HH, part, VV, 1024 / 8, e);
        }
    }
}

// Round 12
// 14964.996 us; speedup vs baseline: 3.2848x; 3.2848x over previous
//
#include <hip/hip_runtime.h>
#include <math.h>

// Problem constants (match reference)
#define BB   256   // batch
#define TT   64    // timesteps
#define SS   256   // encoder seq len
#define VV   512   // vocab
#define EE   512   // embed dim
#define HH   1024  // hidden
#define ENCE 1024  // encoder dim
#define SUME 2048  // summary dim
#define NSP  4     // attention S-splits (round-7 best config)

typedef __attribute__((ext_vector_type(8))) _Float16 h8v;  // 8 fp16 (4 VGPR)
typedef __attribute__((ext_vector_type(4))) float f4v;

// fp32 -> fp16 (hi, lo*2^12) split. x ~= h + l * 2^-12, |err| <= 2^-24 |x|.
__device__ __forceinline__ void split16(float x, _Float16& h, _Float16& l) {
    h = (_Float16)x;
    l = (_Float16)((x - (float)h) * 4096.0f);
}

// ===========================================================================
// LEGACY fp32 path (known-good): decoder_init always; full fallback if ws
// too small.
// ===========================================================================
__global__ __launch_bounds__(256) void gemm2(
    const float* __restrict__ A0, const float* __restrict__ W0, const int K0,
    const int lda0, const int ldw0,
    const float* __restrict__ A1, const float* __restrict__ W1, const int Ktot,
    const int lda1, const int ldw1,
    const float* __restrict__ b0, const float* __restrict__ b1,
    float* __restrict__ C, const int ldc, const int act)
{
    __shared__ float As[16][68];
    __shared__ float Ws[16][68];

    const int tid = threadIdx.x;
    const int n0  = blockIdx.x * 64;
    const int m0  = blockIdx.y * 64;
    const int lr  = tid >> 2;
    const int lc  = (tid & 3) << 2;
    const int tx  = tid & 15;
    const int ty  = tid >> 4;

    float acc[4][4] = {{0.f}};

    for (int k0 = 0; k0 < Ktot; k0 += 16) {
        const float* A; const float* W; int lda, ldw, kk;
        if (k0 < K0) { A = A0; W = W0; lda = lda0; ldw = ldw0; kk = k0; }
        else         { A = A1; W = W1; lda = lda1; ldw = ldw1; kk = k0 - K0; }

        const float4 av = *(const float4*)(A + (size_t)(m0 + lr) * lda + kk + lc);
        const float4 wv = *(const float4*)(W + (size_t)(n0 + lr) * ldw + kk + lc);

        __syncthreads();
        As[lc + 0][lr] = av.x; As[lc + 1][lr] = av.y;
        As[lc + 2][lr] = av.z; As[lc + 3][lr] = av.w;
        Ws[lc + 0][lr] = wv.x; Ws[lc + 1][lr] = wv.y;
        Ws[lc + 2][lr] = wv.z; Ws[lc + 3][lr] = wv.w;
        __syncthreads();

        #pragma unroll
        for (int p = 0; p < 16; ++p) {
            const float4 a4 = *(const float4*)&As[p][ty * 4];
            const float4 w4 = *(const float4*)&Ws[p][tx * 4];
            acc[0][0] += a4.x * w4.x; acc[0][1] += a4.x * w4.y;
            acc[0][2] += a4.x * w4.z; acc[0][3] += a4.x * w4.w;
            acc[1][0] += a4.y * w4.x; acc[1][1] += a4.y * w4.y;
            acc[1][2] += a4.y * w4.z; acc[1][3] += a4.y * w4.w;
            acc[2][0] += a4.z * w4.x; acc[2][1] += a4.z * w4.y;
            acc[2][2] += a4.z * w4.z; acc[2][3] += a4.z * w4.w;
            acc[3][0] += a4.w * w4.x; acc[3][1] += a4.w * w4.y;
            acc[3][2] += a4.w * w4.z; acc[3][3] += a4.w * w4.w;
        }
    }

    float bias[4];
    #pragma unroll
    for (int j = 0; j < 4; ++j) {
        const int n = n0 + tx * 4 + j;
        bias[j] = b0[n] + (b1 ? b1[n] : 0.f);
    }
    #pragma unroll
    for (int i = 0; i < 4; ++i) {
        const int m = m0 + ty * 4 + i;
        #pragma unroll
        for (int j = 0; j < 4; ++j) {
            float v = acc[i][j] + bias[j];
            if (act) v = tanhf(v);
            C[(size_t)m * ldc + n0 + tx * 4 + j] = v;
        }
    }
}

__global__ void lstm_gate(const float* __restrict__ g,
                          float* __restrict__ h, float* __restrict__ c)
{
    const int i = blockIdx.x * blockDim.x + threadIdx.x;
    if (i >= BB * HH) return;
    const int b = i / HH, k = i % HH;
    const float* gb = g + (size_t)b * 4 * HH;
    const float gi = gb[k];
    const float gf = gb[HH + k];
    const float gg = gb[2 * HH + k];
    const float go = gb[3 * HH + k];
    const float si = 1.f / (1.f + expf(-gi));
    const float sf = 1.f / (1.f + expf(-gf));
    const float so = 1.f / (1.f + expf(-go));
    const float cn = sf * c[i] + si * tanhf(gg);
    c[i] = cn;
    h[i] = so * tanhf(cn);
}

// Legacy two-pass fp32 attention (fallback path only).
__global__ __launch_bounds__(256) void attn_kernel(
    const float* __restrict__ q, const float* __restrict__ enc,
    float* __restrict__ cross)
{
    const int b = blockIdx.x, tid = threadIdx.x;
    __shared__ float qs[ENCE];
    __shared__ float sc[SS];
    __shared__ float red[256];

    const float* qb = q + (size_t)b * ENCE;
    const float* eb = enc + (size_t)b * SS * ENCE;

    for (int e = tid; e < ENCE; e += 256) qs[e] = qb[e];
    __syncthreads();

    {
        const float* row = eb + (size_t)tid * ENCE;
        float a = 0.f;
        for (int e = 0; e < ENCE; e += 4) {
            const float4 ev = *(const float4*)&row[e];
            a += ev.x * qs[e] + ev.y * qs[e + 1] + ev.z * qs[e + 2] + ev.w * qs[e + 3];
        }
        sc[tid] = a;
    }
    __syncthreads();

    red[tid] = sc[tid];
    __syncthreads();
    for (int off = 128; off > 0; off >>= 1) {
        if (tid < off) red[tid] = fmaxf(red[tid], red[tid + off]);
        __syncthreads();
    }
    const float mx = red[0];
    __syncthreads();
    const float ex = expf(sc[tid] - mx);
    red[tid] = ex;
    __syncthreads();
    for (int off = 128; off > 0; off >>= 1) {
        if (tid < off) red[tid] += red[tid + off];
        __syncthreads();
    }
    const float inv = 1.f / red[0];
    __syncthreads();
    sc[tid] = ex * inv;
    __syncthreads();

    float4 acc = {0.f, 0.f, 0.f, 0.f};
    const int e0 = tid * 4;
    for (int s = 0; s < SS; ++s) {
        const float w = sc[s];
        const float4 ev = *(const float4*)&eb[(size_t)s * ENCE + e0];
        acc.x += w * ev.x; acc.y += w * ev.y; acc.z += w * ev.z; acc.w += w * ev.w;
    }
    *(float4*)&cross[(size_t)b * ENCE + e0] = acc;
}

// ---------------------------------------------------------------------------
// Split-flash attention (round-7 structure + register prefetch of the next
// 8-row chunk): grid (NSP=4, BB). Block (sp,b) handles s-rows
// [sp*64, sp*64+64). Emits unnormalized partial (m, l, o).
// ---------------------------------------------------------------------------
__global__ __launch_bounds__(256) void attn_part_k(
    const float* __restrict__ q, const float* __restrict__ enc,
    float* __restrict__ po, float* __restrict__ pm, float* __restrict__ pl)
{
    const int sp = blockIdx.x, b = blockIdx.y, tid = threadIdx.x;
    __shared__ float qs[ENCE];
    __shared__ float es[8 * ENCE];   // 32 KB
    __shared__ float sc[8];

    const float* qb = q + (size_t)b * ENCE;
    const float* eb = enc + (size_t)b * SS * ENCE + (size_t)sp * 64 * ENCE;

    *(float4*)&qs[tid * 4] = *(const float4*)&qb[tid * 4];

    // register staging of one 8-row chunk (8 x float4 per thread)
    float4 rg[8];
    auto ldchunk = [&](int ch) {
        const float* src = eb + (size_t)ch * 8 * ENCE + tid * 4;
        #pragma unroll
        for (int i = 0; i < 8; ++i) rg[i] = *(const float4*)(src + i * 1024);
    };
    ldchunk(0);

    const int sl  = tid >> 5;    // 0..7 : row for score phase
    const int seg = tid & 31;    // 0..31: column group
    const int e0  = tid * 4;

    float m = -INFINITY, l = 0.f;
    float4 o = {0.f, 0.f, 0.f, 0.f};

    __syncthreads();   // qs ready

    for (int ch = 0; ch < 8; ++ch) {
        // commit staged registers to LDS
        #pragma unroll
        for (int i = 0; i < 8; ++i)
            *(float4*)&es[tid * 4 + i * 1024] = rg[i];
        __syncthreads();

        if (ch + 1 < 8) ldchunk(ch + 1);   // next chunk in flight under compute

        {   // scores: 32 threads per row
            float a = 0.f;
            const float* row = &es[sl * ENCE];
            #pragma unroll
            for (int j = 0; j < 8; ++j) {
                const int e = seg * 4 + j * 128;
                const float4 ev = *(const float4*)&row[e];
                const float4 qv = *(const float4*)&qs[e];
                a += ev.x * qv.x + ev.y * qv.y + ev.z * qv.z + ev.w * qv.w;
            }
            a += __shfl_xor(a, 1, 32);
            a += __shfl_xor(a, 2, 32);
            a += __shfl_xor(a, 4, 32);
            a += __shfl_xor(a, 8, 32);
            a += __shfl_xor(a, 16, 32);
            if (seg == 0) sc[sl] = a;
        }
        __syncthreads();

        {   // online softmax update (block-uniform m, l)
            float cm = sc[0];
            #pragma unroll
            for (int i = 1; i < 8; ++i) cm = fmaxf(cm, sc[i]);
            const float mn = fmaxf(m, cm);
            const float scale = expf(m - mn);
            o.x *= scale; o.y *= scale; o.z *= scale; o.w *= scale;
            l *= scale;
            float p[8];
            #pragma unroll
            for (int i = 0; i < 8; ++i) { p[i] = expf(sc[i] - mn); l += p[i]; }
            #pragma unroll
            for (int i = 0; i < 8; ++i) {
                const float4 ev = *(const float4*)&es[i * ENCE + e0];
                o.x += p[i] * ev.x; o.y += p[i] * ev.y;
                o.z += p[i] * ev.z; o.w += p[i] * ev.w;
            }
            m = mn;
        }
        __syncthreads();   // all reads done before next chunk's LDS write
    }

    *(float4*)&po[((size_t)sp * BB + b) * ENCE + e0] = o;
    if (tid == 0) { pm[sp * BB + b] = m; pl[sp * BB + b] = l; }
}

// Combine NSP flash partials -> cross fp16 splits (MFMA path).
__global__ __launch_bounds__(256) void attn_comb_k(
    const float* __restrict__ po, const float* __restrict__ pm,
    const float* __restrict__ pl,
    _Float16* __restrict__ crh, _Float16* __restrict__ crl)
{
    const int b = blockIdx.x, tid = threadIdx.x;
    float ms = -INFINITY;
    #pragma unroll
    for (int p = 0; p < NSP; ++p) ms = fmaxf(ms, pm[p * BB + b]);
    float w[NSP]; float L = 0.f;
    #pragma unroll
    for (int p = 0; p < NSP; ++p) {
        w[p] = expf(pm[p * BB + b] - ms);
        L += pl[p * BB + b] * w[p];
    }
    const float inv = 1.f / L;

    const int e0 = tid * 4;
    float4 acc = {0.f, 0.f, 0.f, 0.f};
    #pragma unroll
    for (int p = 0; p < NSP; ++p) {
        const float4 v = *(const float4*)&po[((size_t)p * BB + b) * ENCE + e0];
        acc.x += w[p] * v.x; acc.y += w[p] * v.y;
        acc.z += w[p] * v.z; acc.w += w[p] * v.w;
    }
    const float4 r = {acc.x * inv, acc.y * inv, acc.z * inv, acc.w * inv};

    _Float16 h4[4], l4[4];
    split16(r.x, h4[0], l4[0]); split16(r.y, h4[1], l4[1]);
    split16(r.z, h4[2], l4[2]); split16(r.w, h4[3], l4[3]);
    *(uint2*)&crh[(size_t)b * ENCE + e0] = *(uint2*)h4;
    *(uint2*)&crl[(size_t)b * ENCE + e0] = *(uint2*)l4;
}

// Legacy fallback out projection (fallback path only).
__global__ __launch_bounds__(256) void out_kernel(
    const float* __restrict__ lin, const float* __restrict__ Wout,
    const float* __restrict__ bout, float* __restrict__ tokens,
    float* __restrict__ logits, const int t)
{
    const int b = blockIdx.x, tid = threadIdx.x;
    __shared__ float ls[HH];
    __shared__ float vmax[256];
    __shared__ int   vidx[256];

    const float* lb = lin + (size_t)b * HH;
    for (int e = tid; e < HH; e += 256) ls[e] = lb[e];
    __syncthreads();

    float best = -INFINITY; int bi = 0;
    for (int n = tid; n < VV; n += 256) {
        const float* wr = Wout + (size_t)n * HH;
        float a = bout[n];
        for (int e = 0; e < HH; e += 4) {
            const float4 wv = *(const float4*)&wr[e];
            a += wv.x * ls[e] + wv.y * ls[e + 1] + wv.z * ls[e + 2] + wv.w * ls[e + 3];
        }
        logits[((size_t)b * TT + t) * VV + n] = a;
        if (a > best) { best = a; bi = n; }
    }
    vmax[tid] = best; vidx[tid] = bi;
    __syncthreads();
    for (int off = 128; off > 0; off >>= 1) {
        if (tid < off) {
            const float vo = vmax[tid + off]; const int io = vidx[tid + off];
            if (vo > vmax[tid] || (vo == vmax[tid] && io < vidx[tid])) {
                vmax[tid] = vo; vidx[tid] = io;
            }
        }
        __syncthreads();
    }
    if (tid == 0) tokens[(size_t)b * TT + t] = (float)vidx[0];
}

__global__ void gather_emb(const int* __restrict__ y,
                           const float* __restrict__ table,
                           float* __restrict__ emb, const int t)
{
    const int i = blockIdx.x * blockDim.x + threadIdx.x;
    if (i >= BB * EE) return;
    const int b = i / EE, e = i % EE;
    emb[i] = table[(size_t)y[(size_t)b * TT + t] * EE + e];
}

// init scatter + optional fp16 splits for h0, h1, c1
__global__ void scatter_init_s(const float* __restrict__ ini,
                               float* __restrict__ h0, float* __restrict__ h1,
                               float* __restrict__ c0, float* __restrict__ c1,
                               _Float16* __restrict__ h0h, _Float16* __restrict__ h0l,
                               _Float16* __restrict__ h1h, _Float16* __restrict__ h1l,
                               _Float16* __restrict__ c1h, _Float16* __restrict__ c1l)
{
    const int i = blockIdx.x * blockDim.x + threadIdx.x;
    if (i >= BB * 4 * HH) return;
    const int b = i / (4 * HH), j = i % (4 * HH);
    const int i1 = j / (2 * HH);
    const int rem = j % (2 * HH);
    const int i2 = rem / HH;
    const int k = rem % HH;
    const float v = ini[i];
    const size_t o = (size_t)b * HH + k;
    float* dst = (i1 == 0) ? (i2 == 0 ? h0 : h1) : (i2 == 0 ? c0 : c1);
    dst[o] = v;
    if (h0h) {
        if (i1 == 0) {
            _Float16 h, l; split16(v, h, l);
            if (i2 == 0) { h0h[o] = h; h0l[o] = l; }
            else         { h1h[o] = h; h1l[o] = l; }
        } else if (i2 == 1) {
            _Float16 h, l; split16(v, h, l);
            c1h[o] = h; c1l[o] = l;
        }
    }
}

__global__ void zero_kernel(float* __restrict__ p, const int n)
{
    const int i = blockIdx.x * blockDim.x + threadIdx.x;
    if (i < n) p[i] = 0.f;
}

// ===========================================================================
// fp16 2-split MFMA path: 3 passes, 2 accumulators, fp32-grade (~2^-24).
// ===========================================================================

// fp32 weights -> fp16 (hi, lo*2^12), packed into column slice of [N][dld].
__global__ void conv_w2(const float* __restrict__ src, const int N, const int K,
                        _Float16* __restrict__ dh, _Float16* __restrict__ dl,
                        const int dld, const int coff)
{
    const int total = N * K;
    for (int i = blockIdx.x * blockDim.x + threadIdx.x; i < total;
         i += gridDim.x * blockDim.x) {
        const int n = i / K, k = i - n * K;
        const size_t o = (size_t)n * dld + coff + k;
        split16(src[i], dh[o], dl[o]);
    }
}

// Software-pipelined fp16-split MFMA GEMM, split-K partials.
// If rawA0 != null: A0-side reads fp32 rows of rawA0 at row yidx[m*TT+t]
// (fused embedding gather), split in-registers.
__global__ __launch_bounds__(256) void gemm_f16(
    const _Float16* __restrict__ A0h, const _Float16* __restrict__ A0l, const int lda0,
    const _Float16* __restrict__ A1h, const _Float16* __restrict__ A1l, const int lda1,
    const int K0,
    const float* __restrict__ rawA0, const int* __restrict__ yidx, const int t,
    const _Float16* __restrict__ Wh, const _Float16* __restrict__ Wl,
    const int Kt, float* __restrict__ Cpart, const int N, const int chunk)
{
    __shared__ _Float16 Ash[64][40], Asl[64][40];
    __shared__ _Float16 Wsh[128][40], Wsl[128][40];

    const int tid = threadIdx.x;
    const int n0 = blockIdx.x * 128;
    const int m0 = blockIdx.y * 64;
    const int p  = blockIdx.z;
    const int kbeg = p * chunk, kend = kbeg + chunk;

    const int lane = tid & 63, wave = tid >> 6;
    const int wm = wave >> 1, wn = wave & 1;
    const int l15 = lane & 15, lg = lane >> 4;

    const int ar = tid >> 2, ag = tid & 3;     // staging: row 0..63, k-grp 0..3

    const float* Araw = rawA0
        ? rawA0 + (size_t)yidx[(size_t)(m0 + ar) * TT + t] * lda0 : nullptr;

    f4v accm[2][4], accc[2][4];
    #pragma unroll
    for (int i = 0; i < 2; ++i)
        #pragma unroll
        for (int j = 0; j < 4; ++j) {
            accm[i][j] = (f4v){0.f, 0.f, 0.f, 0.f};
            accc[i][j] = (f4v){0.f, 0.f, 0.f, 0.f};
        }

    uint4 avh, avl, wh0, wl0, wh1, wl1;

    auto load_tile = [&](int kk_) {
        const int col = kk_ + ag * 8;
        if (col < K0) {
            if (Araw) {
                const float4 f0 = *(const float4*)(Araw + col);
                const float4 f1 = *(const float4*)(Araw + col + 4);
                const float xs[8] = {f0.x, f0.y, f0.z, f0.w, f1.x, f1.y, f1.z, f1.w};
                h8v vh, vl;
                #pragma unroll
                for (int j = 0; j < 8; ++j) {
                    _Float16 th, tl;
                    split16(xs[j], th, tl);
                    vh[j] = th;
                    vl[j] = tl;
                }
                avh = *(uint4*)&vh; avl = *(uint4*)&vl;
            } else {
                const size_t o = (size_t)(m0 + ar) * lda0 + col;
                avh = *(const uint4*)(A0h + o);
                avl = *(const uint4*)(A0l + o);
            }
        } else {
            const size_t o = (size_t)(m0 + ar) * lda1 + (col - K0);
            avh = *(const uint4*)(A1h + o);
            avl = *(const uint4*)(A1l + o);
        }
        const size_t o0 = (size_t)(n0 + ar) * Kt + kk_ + ag * 8;
        const size_t o1 = o0 + (size_t)64 * Kt;
        wh0 = *(const uint4*)(Wh + o0);
        wl0 = *(const uint4*)(Wl + o0);
        wh1 = *(const uint4*)(Wh + o1);
        wl1 = *(const uint4*)(Wl + o1);
    };

    load_tile(kbeg);

    for (int kk = kbeg; kk < kend; kk += 32) {
        __syncthreads();

        *(uint4*)&Ash[ar][ag * 8] = avh;
        *(uint4*)&Asl[ar][ag * 8] = avl;
        *(uint4*)&Wsh[ar][ag * 8] = wh0;
        *(uint4*)&Wsl[ar][ag * 8] = wl0;
        *(uint4*)&Wsh[64 + ar][ag * 8] = wh1;
        *(uint4*)&Wsl[64 + ar][ag * 8] = wl1;

        __syncthreads();

        if (kk + 32 < kend) load_tile(kk + 32);   // in flight under compute

        h8v afh[2], afl[2];
        #pragma unroll
        for (int fr = 0; fr < 2; ++fr) {
            const int r = wm * 32 + fr * 16 + l15;
            afh[fr] = *(const h8v*)&Ash[r][lg * 8];
            afl[fr] = *(const h8v*)&Asl[r][lg * 8];
        }
        #pragma unroll
        for (int fn = 0; fn < 4; ++fn) {
            const int r = wn * 64 + fn * 16 + l15;
            const h8v wfh = *(const h8v*)&Wsh[r][lg * 8];
            const h8v wfl = *(const h8v*)&Wsl[r][lg * 8];
            #pragma unroll
            for (int fr = 0; fr < 2; ++fr) {
                accm[fr][fn] = __builtin_amdgcn_mfma_f32_16x16x32_f16(
                    afh[fr], wfh, accm[fr][fn], 0, 0, 0);
                accc[fr][fn] = __builtin_amdgcn_mfma_f32_16x16x32_f16(
                    afh[fr], wfl, accc[fr][fn], 0, 0, 0);
                accc[fr][fn] = __builtin_amdgcn_mfma_f32_16x16x32_f16(
                    afl[fr], wfh, accc[fr][fn], 0, 0, 0);
            }
        }
    }

    const float s12 = 0.000244140625f;  // 2^-12
    float* slab = Cpart + (size_t)p * BB * N;
    #pragma unroll
    for (int fr = 0; fr < 2; ++fr) {
        const int row0 = m0 + wm * 32 + fr * 16 + lg * 4;
        #pragma unroll
        for (int fn = 0; fn < 4; ++fn) {
            const int col = n0 + wn * 64 + fn * 16 + l15;
            #pragma unroll
            for (int j = 0; j < 4; ++j)
                slab[(size_t)(row0 + j) * N + col] =
                    accm[fr][fn][j] + s12 * accc[fr][fn][j];
        }
    }
}

// split-K reduce + bias + tanh; dst and split outputs each optional
__global__ void ep_tanh_s(const float* __restrict__ part, const int P,
                          const float* __restrict__ bias, float* __restrict__ dst,
                          _Float16* __restrict__ dh, _Float16* __restrict__ dl,
                          const int total, const int N)
{
    for (int i = blockIdx.x * blockDim.x + threadIdx.x; i < total;
         i += gridDim.x * blockDim.x) {
        const int n = i % N;
        float s = bias[n];
        for (int p = 0; p < P; ++p) s += part[(size_t)p * total + i];
        const float v = tanhf(s);
        if (dst) dst[i] = v;
        if (dh) split16(v, dh[i], dl[i]);
    }
}

// split-K reduce + biases + LSTM gate pointwise + fp16 split emission
__global__ void ep_gate_s(const float* __restrict__ part, const int P,
                          const float* __restrict__ bih, const float* __restrict__ bhh,
                          float* __restrict__ h, float* __restrict__ c,
                          _Float16* __restrict__ hh, _Float16* __restrict__ hl,
                          _Float16* __restrict__ ch, _Float16* __restrict__ cl)
{
    const int i = blockIdx.x * blockDim.x + threadIdx.x;
    if (i >= BB * HH) return;
    const int b = i >> 10, k = i & (HH - 1);
    const size_t base = (size_t)b * 4 * HH;
    float gi = bih[k] + bhh[k];
    float gf = bih[HH + k] + bhh[HH + k];
    float gg = bih[2 * HH + k] + bhh[2 * HH + k];
    float go = bih[3 * HH + k] + bhh[3 * HH + k];
    for (int p = 0; p < P; ++p) {
        const float* gp = part + (size_t)p * BB * 4 * HH + base;
        gi += gp[k]; gf += gp[HH + k]; gg += gp[2 * HH + k]; go += gp[3 * HH + k];
    }
    const float si = 1.f / (1.f + expf(-gi));
    const float sf = 1.f / (1.f + expf(-gf));
    const float so = 1.f / (1.f + expf(-go));
    const float cn = sf * c[i] + si * tanhf(gg);
    const float hn = so * tanhf(cn);
    c[i] = cn;
    h[i] = hn;
    split16(hn, hh[i], hl[i]);
    if (ch) split16(cn, ch[i], cl[i]);
}

// split-K reduce + bias + logits write + first-max argmax. One block per b.
__global__ __launch_bounds__(256) void ep_argmax(
    const float* __restrict__ part, const int P,
    const float* __restrict__ bias, float* __restrict__ tokens,
    float* __restrict__ logits, const int t)
{
    const int b = blockIdx.x, tid = threadIdx.x;
    __shared__ float vmax[256];
    __shared__ int   vidx[256];

    float best = -INFINITY; int bi = 0;
    #pragma unroll
    for (int j = 0; j < 2; ++j) {
        const int n = tid + j * 256;
        float s = bias[n];
        for (int p = 0; p < P; ++p)
            s += part[(size_t)p * BB * VV + (size_t)b * VV + n];
        logits[((size_t)b * TT + t) * VV + n] = s;
        if (s > best) { best = s; bi = n; }   // ascending n: first-max kept
    }
    vmax[tid] = best; vidx[tid] = bi;
    __syncthreads();
    for (int off = 128; off > 0; off >>= 1) {
        if (tid < off) {
            const float vo = vmax[tid + off]; const int io = vidx[tid + off];
            if (vo > vmax[tid] || (vo == vmax[tid] && io < vidx[tid])) {
                vmax[tid] = vo; vidx[tid] = io;
            }
        }
        __syncthreads();
    }
    if (tid == 0) tokens[(size_t)b * TT + t] = (float)vidx[0];
}

// ===========================================================================
extern "C" void kernel_launch(void* const* d_in, const int* in_sizes, int n_in,
                              void* d_out, int out_size, void* d_ws, size_t ws_size,
                              hipStream_t stream)
{
    const int*   y         = (const int*)  d_in[0];
    const float* enc       = (const float*)d_in[1];
    const float* esum      = (const float*)d_in[2];
    const float* emb_table = (const float*)d_in[3];
    const float* W_init    = (const float*)d_in[4];
    const float* b_init    = (const float*)d_in[5];
    const float* W_ci      = (const float*)d_in[6];
    const float* b_ci      = (const float*)d_in[7];
    const float* Wih0      = (const float*)d_in[8];
    const float* Whh0      = (const float*)d_in[9];
    const float* bih0      = (const float*)d_in[10];
    const float* bhh0      = (const float*)d_in[11];
    const float* Wih1      = (const float*)d_in[12];
    const float* Whh1      = (const float*)d_in[13];
    const float* bih1      = (const float*)d_in[14];
    const float* bhh1      = (const float*)d_in[15];
    const float* Wq        = (const float*)d_in[16];
    const float* bq        = (const float*)d_in[17];
    const float* Wco       = (const float*)d_in[18];
    const float* bco       = (const float*)d_in[19];
    const float* Wout      = (const float*)d_in[20];
    const float* bout      = (const float*)d_in[21];

    float* out    = (float*)d_out;
    float* tokens = out;
    float* logits = out + (size_t)BB * TT;

    // ---- workspace carve ----
    char* wsb = (char*)d_ws;
    size_t off = 0;
    auto alloc = [&](size_t bytes) -> char* {
        char* p = wsb + off;
        off = (off + bytes + 255) & ~(size_t)255;
        return p;
    };
    float* h0    = (float*)alloc((size_t)BB * HH * 4);
    float* h1    = (float*)alloc((size_t)BB * HH * 4);
    float* c0    = (float*)alloc((size_t)BB * HH * 4);
    float* c1    = (float*)alloc((size_t)BB * HH * 4);
    float* cross = (float*)alloc((size_t)BB * ENCE * 4);
    float* xbuf  = (float*)alloc((size_t)BB * EE * 4);
    float* embb  = (float*)alloc((size_t)BB * EE * 4);
    float* gbuf  = (float*)alloc((size_t)BB * 4 * HH * 4);
    float* qbuf  = (float*)alloc((size_t)BB * ENCE * 4);

    float* part = (float*)alloc((size_t)16 * BB * HH * 4);   // 16 MiB

    // fp16 weight splits, row-major [N][ld]
    _Float16 *ci_h, *ci_l, *g0_h, *g0_l, *g1_h, *g1_l, *wq_h, *wq_l,
             *wc_h, *wc_l, *wo_h, *wo_l;
    ci_h = (_Float16*)alloc((size_t)EE * 1536 * 2);
    ci_l = (_Float16*)alloc((size_t)EE * 1536 * 2);
    g0_h = (_Float16*)alloc((size_t)4 * HH * 1536 * 2);
    g0_l = (_Float16*)alloc((size_t)4 * HH * 1536 * 2);
    g1_h = (_Float16*)alloc((size_t)4 * HH * 2048 * 2);
    g1_l = (_Float16*)alloc((size_t)4 * HH * 2048 * 2);
    wq_h = (_Float16*)alloc((size_t)ENCE * 2048 * 2);
    wq_l = (_Float16*)alloc((size_t)ENCE * 2048 * 2);
    wc_h = (_Float16*)alloc((size_t)HH * 2048 * 2);
    wc_l = (_Float16*)alloc((size_t)HH * 2048 * 2);
    wo_h = (_Float16*)alloc((size_t)VV * HH * 2);
    wo_l = (_Float16*)alloc((size_t)VV * HH * 2);

    // fp16 activation splits
    _Float16* xbh  = (_Float16*)alloc((size_t)BB * EE * 2);
    _Float16* xbl  = (_Float16*)alloc((size_t)BB * EE * 2);
    _Float16* h0h  = (_Float16*)alloc((size_t)BB * HH * 2);
    _Float16* h0l  = (_Float16*)alloc((size_t)BB * HH * 2);
    _Float16* h1h  = (_Float16*)alloc((size_t)BB * HH * 2);
    _Float16* h1l  = (_Float16*)alloc((size_t)BB * HH * 2);
    _Float16* c1h  = (_Float16*)alloc((size_t)BB * HH * 2);
    _Float16* c1l  = (_Float16*)alloc((size_t)BB * HH * 2);
    _Float16* crh  = (_Float16*)alloc((size_t)BB * ENCE * 2);
    _Float16* crl  = (_Float16*)alloc((size_t)BB * ENCE * 2);
    _Float16* lnh  = (_Float16*)alloc((size_t)BB * HH * 2);
    _Float16* lnl  = (_Float16*)alloc((size_t)BB * HH * 2);

    // attention partials
    float* po = (float*)alloc((size_t)NSP * BB * ENCE * 4);
    float* pm = (float*)alloc((size_t)NSP * BB * 4);
    float* pl = (float*)alloc((size_t)NSP * BB * 4);
    const size_t need_mfma = off;

    const int mfma_ok = (ws_size >= need_mfma);

    const dim3 thr(256);

    // ---- decoder_init (fp32, once) ----
    gemm2<<<dim3(4 * HH / 64, BB / 64), thr, 0, stream>>>(
        esum, W_init, SUME, SUME, SUME,
        nullptr, nullptr, SUME, 0, 0,
        b_init, nullptr, gbuf, 4 * HH, 1);
    scatter_init_s<<<dim3(BB * 4 * HH / 256), thr, 0, stream>>>(
        gbuf, h0, h1, c0, c1,
        mfma_ok ? h0h : nullptr, h0l, h1h, h1l, c1h, c1l);
    zero_kernel<<<dim3(BB * ENCE / 256), thr, 0, stream>>>(cross, BB * ENCE);

    if (!mfma_ok) {
        for (int t = 0; t < TT; ++t) {
            gather_emb<<<dim3(BB * EE / 256), thr, 0, stream>>>(y, emb_table, embb, t);
            gemm2<<<dim3(EE / 64, BB / 64), thr, 0, stream>>>(
                embb, W_ci, EE, EE, EE + ENCE,
                cross, W_ci + EE, EE + ENCE, ENCE, EE + ENCE,
                b_ci, nullptr, xbuf, EE, 1);
            gemm2<<<dim3(4 * HH / 64, BB / 64), thr, 0, stream>>>(
                xbuf, Wih0, EE, EE, EE,
                h0, Whh0, EE + HH, HH, HH,
                bih0, bhh0, gbuf, 4 * HH, 0);
            lstm_gate<<<dim3(BB * HH / 256), thr, 0, stream>>>(gbuf, h0, c0);
            gemm2<<<dim3(4 * HH / 64, BB / 64), thr, 0, stream>>>(
                h0, Wih1, HH, HH, HH,
                h1, Whh1, 2 * HH, HH, HH,
                bih1, bhh1, gbuf, 4 * HH, 0);
            lstm_gate<<<dim3(BB * HH / 256), thr, 0, stream>>>(gbuf, h1, c1);
            gemm2<<<dim3(ENCE / 64, BB / 64), thr, 0, stream>>>(
                h1, Wq, HH, HH, 2 * HH,
                c1, Wq + HH, 2 * HH, HH, 2 * HH,
                bq, nullptr, qbuf, ENCE, 1);
            attn_kernel<<<dim3(BB), thr, 0, stream>>>(qbuf, enc, cross);
            gemm2<<<dim3(HH / 64, BB / 64), thr, 0, stream>>>(
                h1, Wco, HH, HH, ENCE + HH,
                cross, Wco + HH, ENCE + HH, ENCE, ENCE + HH,
                bco, nullptr, qbuf, HH, 1);
            out_kernel<<<dim3(BB), thr, 0, stream>>>(qbuf, Wout, bout, tokens, logits, t);
        }
        return;
    }

    // ---- one-time weight fp16-splits ----
    const dim3 cg(4096);
    conv_w2<<<cg, thr, 0, stream>>>(W_ci, EE, EE + ENCE, ci_h, ci_l, 1536, 0);
    conv_w2<<<cg, thr, 0, stream>>>(Wih0, 4 * HH, EE, g0_h, g0_l, 1536, 0);
    conv_w2<<<cg, thr, 0, stream>>>(Whh0, 4 * HH, HH, g0_h, g0_l, 1536, EE);
    conv_w2<<<cg, thr, 0, stream>>>(Wih1, 4 * HH, HH, g1_h, g1_l, 2048, 0);
    conv_w2<<<cg, thr, 0, stream>>>(Whh1, 4 * HH, HH, g1_h, g1_l, 2048, HH);
    conv_w2<<<cg, thr, 0, stream>>>(Wq, ENCE, 2 * HH, wq_h, wq_l, 2048, 0);
    conv_w2<<<cg, thr, 0, stream>>>(Wco, HH, ENCE + HH, wc_h, wc_l, 2048, 0);
    conv_w2<<<cg, thr, 0, stream>>>(Wout, VV, HH, wo_h, wo_l, HH, 0);
    // cross = 0 at t=0 (fp16 zero == bits zero)
    zero_kernel<<<dim3(BB * ENCE / 512), thr, 0, stream>>>((float*)crh, BB * ENCE / 2);
    zero_kernel<<<dim3(BB * ENCE / 512), thr, 0, stream>>>((float*)crl, BB * ENCE / 2);

    auto gemmS = [&](const _Float16* a0h, const _Float16* a0l, int lda0,
                     const _Float16* a1h, const _Float16* a1l, int lda1, int K0,
                     const float* raw0, const int* yi, int t_,
                     const _Float16* wh, const _Float16* wl,
                     int Kt, int N, int P) {
        gemm_f16<<<dim3(N / 128, BB / 64, P), thr, 0, stream>>>(
            a0h, a0l, lda0, a1h, a1l, lda1, K0, raw0, yi, t_,
            wh, wl, Kt, part, N, Kt / P);
    };

    for (int t = 0; t < TT; ++t) {
        // x = tanh([emb_table[y[:,t]] | cross] @ Wci^T + b_ci)  (fused gather)
        gemmS(nullptr, nullptr, EE, crh, crl, ENCE, EE,
              emb_table, y, t, ci_h, ci_l, 1536, EE, 8);
        ep_tanh_s<<<dim3(512), thr, 0, stream>>>(part, 8, b_ci, nullptr, xbh, xbl,
                                                 BB * EE, EE);

        // layer0 gates
        gemmS(xbh, xbl, EE, h0h, h0l, HH, EE, nullptr, nullptr, 0,
              g0_h, g0_l, 1536, 4 * HH, 4);
        ep_gate_s<<<dim3(BB * HH / 256), thr, 0, stream>>>(
            part, 4, bih0, bhh0, h0, c0, h0h, h0l, nullptr, nullptr);

        // layer1 gates
        gemmS(h0h, h0l, HH, h1h, h1l, HH, HH, nullptr, nullptr, 0,
              g1_h, g1_l, 2048, 4 * HH, 4);
        ep_gate_s<<<dim3(BB * HH / 256), thr, 0, stream>>>(
            part, 4, bih1, bhh1, h1, c1, h1h, h1l, c1h, c1l);

        // q = tanh([h1 | c1] @ Wq^T + bq)  (fp32 q for attention)
        gemmS(h1h, h1l, HH, c1h, c1l, HH, HH, nullptr, nullptr, 0,
              wq_h, wq_l, 2048, ENCE, 8);
        ep_tanh_s<<<dim3(1024), thr, 0, stream>>>(part, 8, bq, qbuf, nullptr, nullptr,
                                                  BB * ENCE, ENCE);

        // attention: split-flash partials + combine -> cross splits
        attn_part_k<<<dim3(NSP, BB), thr, 0, stream>>>(qbuf, enc, po, pm, pl);
        attn_comb_k<<<dim3(BB), thr, 0, stream>>>(po, pm, pl, crh, crl);

        // lin = tanh([h1 | cross] @ Wco^T + bco) -> splits only
        gemmS(h1h, h1l, HH, crh, crl, ENCE, HH, nullptr, nullptr, 0,
              wc_h, wc_l, 2048, HH, 8);
        ep_tanh_s<<<dim3(1024), thr, 0, stream>>>(part, 8, bco, nullptr, lnh, lnl,
                                                  BB * HH, HH);

        // logits GEMM + fused argmax epilogue
        gemmS(lnh, lnl, HH, nullptr, nullptr, HH, HH, nullptr, nullptr, 0,
              wo_h, wo_l, HH, VV, 8);
        ep_argmax<<<dim3(BB), thr, 0, stream>>>(part, 8, bout, tokens, logits, t);
    }
}

// Round 13
// 11425.855 us; speedup vs baseline: 4.3022x; 1.3097x over previous
//
#include <hip/hip_runtime.h>
#include <math.h>

// Problem constants (match reference)
#define BB   256   // batch
#define TT   64    // timesteps
#define SS   256   // encoder seq len
#define VV   512   // vocab
#define EE   512   // embed dim
#define HH   1024  // hidden
#define ENCE 1024  // encoder dim
#define SUME 2048  // summary dim
#define NSP  4     // attention S-splits (round-7 best config)

typedef __attribute__((ext_vector_type(8))) _Float16 h8v;  // 8 fp16 (4 VGPR)
typedef __attribute__((ext_vector_type(4))) float f4v;

// fp32 -> fp16 (hi, lo*2^12) split. x ~= h + l * 2^-12, |err| <= 2^-24 |x|.
__device__ __forceinline__ void split16(float x, _Float16& h, _Float16& l) {
    h = (_Float16)x;
    l = (_Float16)((x - (float)h) * 4096.0f);
}

// ===========================================================================
// LEGACY fp32 path (known-good): decoder_init always; full fallback if ws
// too small.
// ===========================================================================
__global__ __launch_bounds__(256) void gemm2(
    const float* __restrict__ A0, const float* __restrict__ W0, const int K0,
    const int lda0, const int ldw0,
    const float* __restrict__ A1, const float* __restrict__ W1, const int Ktot,
    const int lda1, const int ldw1,
    const float* __restrict__ b0, const float* __restrict__ b1,
    float* __restrict__ C, const int ldc, const int act)
{
    __shared__ float As[16][68];
    __shared__ float Ws[16][68];

    const int tid = threadIdx.x;
    const int n0  = blockIdx.x * 64;
    const int m0  = blockIdx.y * 64;
    const int lr  = tid >> 2;
    const int lc  = (tid & 3) << 2;
    const int tx  = tid & 15;
    const int ty  = tid >> 4;

    float acc[4][4] = {{0.f}};

    for (int k0 = 0; k0 < Ktot; k0 += 16) {
        const float* A; const float* W; int lda, ldw, kk;
        if (k0 < K0) { A = A0; W = W0; lda = lda0; ldw = ldw0; kk = k0; }
        else         { A = A1; W = W1; lda = lda1; ldw = ldw1; kk = k0 - K0; }

        const float4 av = *(const float4*)(A + (size_t)(m0 + lr) * lda + kk + lc);
        const float4 wv = *(const float4*)(W + (size_t)(n0 + lr) * ldw + kk + lc);

        __syncthreads();
        As[lc + 0][lr] = av.x; As[lc + 1][lr] = av.y;
        As[lc + 2][lr] = av.z; As[lc + 3][lr] = av.w;
        Ws[lc + 0][lr] = wv.x; Ws[lc + 1][lr] = wv.y;
        Ws[lc + 2][lr] = wv.z; Ws[lc + 3][lr] = wv.w;
        __syncthreads();

        #pragma unroll
        for (int p = 0; p < 16; ++p) {
            const float4 a4 = *(const float4*)&As[p][ty * 4];
            const float4 w4 = *(const float4*)&Ws[p][tx * 4];
            acc[0][0] += a4.x * w4.x; acc[0][1] += a4.x * w4.y;
            acc[0][2] += a4.x * w4.z; acc[0][3] += a4.x * w4.w;
            acc[1][0] += a4.y * w4.x; acc[1][1] += a4.y * w4.y;
            acc[1][2] += a4.y * w4.z; acc[1][3] += a4.y * w4.w;
            acc[2][0] += a4.z * w4.x; acc[2][1] += a4.z * w4.y;
            acc[2][2] += a4.z * w4.z; acc[2][3] += a4.z * w4.w;
            acc[3][0] += a4.w * w4.x; acc[3][1] += a4.w * w4.y;
            acc[3][2] += a4.w * w4.z; acc[3][3] += a4.w * w4.w;
        }
    }

    float bias[4];
    #pragma unroll
    for (int j = 0; j < 4; ++j) {
        const int n = n0 + tx * 4 + j;
        bias[j] = b0[n] + (b1 ? b1[n] : 0.f);
    }
    #pragma unroll
    for (int i = 0; i < 4; ++i) {
        const int m = m0 + ty * 4 + i;
        #pragma unroll
        for (int j = 0; j < 4; ++j) {
            float v = acc[i][j] + bias[j];
            if (act) v = tanhf(v);
            C[(size_t)m * ldc + n0 + tx * 4 + j] = v;
        }
    }
}

__global__ void lstm_gate(const float* __restrict__ g,
                          float* __restrict__ h, float* __restrict__ c)
{
    const int i = blockIdx.x * blockDim.x + threadIdx.x;
    if (i >= BB * HH) return;
    const int b = i / HH, k = i % HH;
    const float* gb = g + (size_t)b * 4 * HH;
    const float gi = gb[k];
    const float gf = gb[HH + k];
    const float gg = gb[2 * HH + k];
    const float go = gb[3 * HH + k];
    const float si = 1.f / (1.f + expf(-gi));
    const float sf = 1.f / (1.f + expf(-gf));
    const float so = 1.f / (1.f + expf(-go));
    const float cn = sf * c[i] + si * tanhf(gg);
    c[i] = cn;
    h[i] = so * tanhf(cn);
}

// Legacy two-pass fp32 attention (fallback path only).
__global__ __launch_bounds__(256) void attn_kernel(
    const float* __restrict__ q, const float* __restrict__ enc,
    float* __restrict__ cross)
{
    const int b = blockIdx.x, tid = threadIdx.x;
    __shared__ float qs[ENCE];
    __shared__ float sc[SS];
    __shared__ float red[256];

    const float* qb = q + (size_t)b * ENCE;
    const float* eb = enc + (size_t)b * SS * ENCE;

    for (int e = tid; e < ENCE; e += 256) qs[e] = qb[e];
    __syncthreads();

    {
        const float* row = eb + (size_t)tid * ENCE;
        float a = 0.f;
        for (int e = 0; e < ENCE; e += 4) {
            const float4 ev = *(const float4*)&row[e];
            a += ev.x * qs[e] + ev.y * qs[e + 1] + ev.z * qs[e + 2] + ev.w * qs[e + 3];
        }
        sc[tid] = a;
    }
    __syncthreads();

    red[tid] = sc[tid];
    __syncthreads();
    for (int off = 128; off > 0; off >>= 1) {
        if (tid < off) red[tid] = fmaxf(red[tid], red[tid + off]);
        __syncthreads();
    }
    const float mx = red[0];
    __syncthreads();
    const float ex = expf(sc[tid] - mx);
    red[tid] = ex;
    __syncthreads();
    for (int off = 128; off > 0; off >>= 1) {
        if (tid < off) red[tid] += red[tid + off];
        __syncthreads();
    }
    const float inv = 1.f / red[0];
    __syncthreads();
    sc[tid] = ex * inv;
    __syncthreads();

    float4 acc = {0.f, 0.f, 0.f, 0.f};
    const int e0 = tid * 4;
    for (int s = 0; s < SS; ++s) {
        const float w = sc[s];
        const float4 ev = *(const float4*)&eb[(size_t)s * ENCE + e0];
        acc.x += w * ev.x; acc.y += w * ev.y; acc.z += w * ev.z; acc.w += w * ev.w;
    }
    *(float4*)&cross[(size_t)b * ENCE + e0] = acc;
}

// ---------------------------------------------------------------------------
// Split-flash attention (round-7 best): grid (NSP=4, BB). Block (sp,b)
// handles s-rows [sp*64, sp*64+64) in 8-row LDS chunks (36 KB), emits
// unnormalized partial (m, l, o).
// ---------------------------------------------------------------------------
__global__ __launch_bounds__(256) void attn_part_k(
    const float* __restrict__ q, const float* __restrict__ enc,
    float* __restrict__ po, float* __restrict__ pm, float* __restrict__ pl)
{
    const int sp = blockIdx.x, b = blockIdx.y, tid = threadIdx.x;
    __shared__ float qs[ENCE];
    __shared__ float es[8 * ENCE];   // 32 KB
    __shared__ float sc[8];

    const float* qb = q + (size_t)b * ENCE;
    const float* eb = enc + (size_t)b * SS * ENCE + (size_t)sp * 64 * ENCE;

    *(float4*)&qs[tid * 4] = *(const float4*)&qb[tid * 4];
    __syncthreads();

    const int sl  = tid >> 5;    // 0..7 : row for score phase
    const int seg = tid & 31;    // 0..31: column group
    const int e0  = tid * 4;

    float m = -INFINITY, l = 0.f;
    float4 o = {0.f, 0.f, 0.f, 0.f};

    for (int ch = 0; ch < 8; ++ch) {
        {   // stage 8 rows, fully coalesced
            const float* src = eb + (size_t)ch * 8 * ENCE;
            #pragma unroll
            for (int i = 0; i < 8; ++i) {
                const int idx = tid * 4 + i * 1024;
                *(float4*)&es[idx] = *(const float4*)&src[idx];
            }
        }
        __syncthreads();

        {   // scores: 32 threads per row
            float a = 0.f;
            const float* row = &es[sl * ENCE];
            #pragma unroll
            for (int j = 0; j < 8; ++j) {
                const int e = seg * 4 + j * 128;
                const float4 ev = *(const float4*)&row[e];
                const float4 qv = *(const float4*)&qs[e];
                a += ev.x * qv.x + ev.y * qv.y + ev.z * qv.z + ev.w * qv.w;
            }
            a += __shfl_xor(a, 1, 32);
            a += __shfl_xor(a, 2, 32);
            a += __shfl_xor(a, 4, 32);
            a += __shfl_xor(a, 8, 32);
            a += __shfl_xor(a, 16, 32);
            if (seg == 0) sc[sl] = a;
        }
        __syncthreads();

        {   // online softmax update (block-uniform m, l)
            float cm = sc[0];
            #pragma unroll
            for (int i = 1; i < 8; ++i) cm = fmaxf(cm, sc[i]);
            const float mn = fmaxf(m, cm);
            const float scale = expf(m - mn);
            o.x *= scale; o.y *= scale; o.z *= scale; o.w *= scale;
            l *= scale;
            float p[8];
            #pragma unroll
            for (int i = 0; i < 8; ++i) { p[i] = expf(sc[i] - mn); l += p[i]; }
            #pragma unroll
            for (int i = 0; i < 8; ++i) {
                const float4 ev = *(const float4*)&es[i * ENCE + e0];
                o.x += p[i] * ev.x; o.y += p[i] * ev.y;
                o.z += p[i] * ev.z; o.w += p[i] * ev.w;
            }
            m = mn;
        }
        __syncthreads();
    }

    *(float4*)&po[((size_t)sp * BB + b) * ENCE + e0] = o;
    if (tid == 0) { pm[sp * BB + b] = m; pl[sp * BB + b] = l; }
}

// Combine NSP flash partials -> cross fp16 splits (MFMA path).
__global__ __launch_bounds__(256) void attn_comb_k(
    const float* __restrict__ po, const float* __restrict__ pm,
    const float* __restrict__ pl,
    _Float16* __restrict__ crh, _Float16* __restrict__ crl)
{
    const int b = blockIdx.x, tid = threadIdx.x;
    float ms = -INFINITY;
    #pragma unroll
    for (int p = 0; p < NSP; ++p) ms = fmaxf(ms, pm[p * BB + b]);
    float w[NSP]; float L = 0.f;
    #pragma unroll
    for (int p = 0; p < NSP; ++p) {
        w[p] = expf(pm[p * BB + b] - ms);
        L += pl[p * BB + b] * w[p];
    }
    const float inv = 1.f / L;

    const int e0 = tid * 4;
    float4 acc = {0.f, 0.f, 0.f, 0.f};
    #pragma unroll
    for (int p = 0; p < NSP; ++p) {
        const float4 v = *(const float4*)&po[((size_t)p * BB + b) * ENCE + e0];
        acc.x += w[p] * v.x; acc.y += w[p] * v.y;
        acc.z += w[p] * v.z; acc.w += w[p] * v.w;
    }
    const float4 r = {acc.x * inv, acc.y * inv, acc.z * inv, acc.w * inv};

    _Float16 h4[4], l4[4];
    split16(r.x, h4[0], l4[0]); split16(r.y, h4[1], l4[1]);
    split16(r.z, h4[2], l4[2]); split16(r.w, h4[3], l4[3]);
    *(uint2*)&crh[(size_t)b * ENCE + e0] = *(uint2*)h4;
    *(uint2*)&crl[(size_t)b * ENCE + e0] = *(uint2*)l4;
}

// Legacy fallback out projection (fallback path only).
__global__ __launch_bounds__(256) void out_kernel(
    const float* __restrict__ lin, const float* __restrict__ Wout,
    const float* __restrict__ bout, float* __restrict__ tokens,
    float* __restrict__ logits, const int t)
{
    const int b = blockIdx.x, tid = threadIdx.x;
    __shared__ float ls[HH];
    __shared__ float vmax[256];
    __shared__ int   vidx[256];

    const float* lb = lin + (size_t)b * HH;
    for (int e = tid; e < HH; e += 256) ls[e] = lb[e];
    __syncthreads();

    float best = -INFINITY; int bi = 0;
    for (int n = tid; n < VV; n += 256) {
        const float* wr = Wout + (size_t)n * HH;
        float a = bout[n];
        for (int e = 0; e < HH; e += 4) {
            const float4 wv = *(const float4*)&wr[e];
            a += wv.x * ls[e] + wv.y * ls[e + 1] + wv.z * ls[e + 2] + wv.w * ls[e + 3];
        }
        logits[((size_t)b * TT + t) * VV + n] = a;
        if (a > best) { best = a; bi = n; }
    }
    vmax[tid] = best; vidx[tid] = bi;
    __syncthreads();
    for (int off = 128; off > 0; off >>= 1) {
        if (tid < off) {
            const float vo = vmax[tid + off]; const int io = vidx[tid + off];
            if (vo > vmax[tid] || (vo == vmax[tid] && io < vidx[tid])) {
                vmax[tid] = vo; vidx[tid] = io;
            }
        }
        __syncthreads();
    }
    if (tid == 0) tokens[(size_t)b * TT + t] = (float)vidx[0];
}

__global__ void gather_emb(const int* __restrict__ y,
                           const float* __restrict__ table,
                           float* __restrict__ emb, const int t)
{
    const int i = blockIdx.x * blockDim.x + threadIdx.x;
    if (i >= BB * EE) return;
    const int b = i / EE, e = i % EE;
    emb[i] = table[(size_t)y[(size_t)b * TT + t] * EE + e];
}

// init scatter + optional fp16 splits for h0, h1, c1
__global__ void scatter_init_s(const float* __restrict__ ini,
                               float* __restrict__ h0, float* __restrict__ h1,
                               float* __restrict__ c0, float* __restrict__ c1,
                               _Float16* __restrict__ h0h, _Float16* __restrict__ h0l,
                               _Float16* __restrict__ h1h, _Float16* __restrict__ h1l,
                               _Float16* __restrict__ c1h, _Float16* __restrict__ c1l)
{
    const int i = blockIdx.x * blockDim.x + threadIdx.x;
    if (i >= BB * 4 * HH) return;
    const int b = i / (4 * HH), j = i % (4 * HH);
    const int i1 = j / (2 * HH);
    const int rem = j % (2 * HH);
    const int i2 = rem / HH;
    const int k = rem % HH;
    const float v = ini[i];
    const size_t o = (size_t)b * HH + k;
    float* dst = (i1 == 0) ? (i2 == 0 ? h0 : h1) : (i2 == 0 ? c0 : c1);
    dst[o] = v;
    if (h0h) {
        if (i1 == 0) {
            _Float16 h, l; split16(v, h, l);
            if (i2 == 0) { h0h[o] = h; h0l[o] = l; }
            else         { h1h[o] = h; h1l[o] = l; }
        } else if (i2 == 1) {
            _Float16 h, l; split16(v, h, l);
            c1h[o] = h; c1l[o] = l;
        }
    }
}

__global__ void zero_kernel(float* __restrict__ p, const int n)
{
    const int i = blockIdx.x * blockDim.x + threadIdx.x;
    if (i < n) p[i] = 0.f;
}

// ===========================================================================
// fp16 2-split MFMA path: 3 passes, 2 accumulators, fp32-grade (~2^-24).
// ===========================================================================

// fp32 weights -> fp16 (hi, lo*2^12), packed into column slice of [N][dld].
__global__ void conv_w2(const float* __restrict__ src, const int N, const int K,
                        _Float16* __restrict__ dh, _Float16* __restrict__ dl,
                        const int dld, const int coff)
{
    const int total = N * K;
    for (int i = blockIdx.x * blockDim.x + threadIdx.x; i < total;
         i += gridDim.x * blockDim.x) {
        const int n = i / K, k = i - n * K;
        const size_t o = (size_t)n * dld + coff + k;
        split16(src[i], dh[o], dl[o]);
    }
}

// Software-pipelined fp16-split MFMA GEMM, split-K partials.
// If rawA0 != null: A0-side reads fp32 rows of rawA0 at row yidx[m*TT+t]
// (fused embedding gather), split in-registers.
__global__ __launch_bounds__(256) void gemm_f16(
    const _Float16* __restrict__ A0h, const _Float16* __restrict__ A0l, const int lda0,
    const _Float16* __restrict__ A1h, const _Float16* __restrict__ A1l, const int lda1,
    const int K0,
    const float* __restrict__ rawA0, const int* __restrict__ yidx, const int t,
    const _Float16* __restrict__ Wh, const _Float16* __restrict__ Wl,
    const int Kt, float* __restrict__ Cpart, const int N, const int chunk)
{
    __shared__ _Float16 Ash[64][40], Asl[64][40];
    __shared__ _Float16 Wsh[128][40], Wsl[128][40];

    const int tid = threadIdx.x;
    const int n0 = blockIdx.x * 128;
    const int m0 = blockIdx.y * 64;
    const int p  = blockIdx.z;
    const int kbeg = p * chunk, kend = kbeg + chunk;

    const int lane = tid & 63, wave = tid >> 6;
    const int wm = wave >> 1, wn = wave & 1;
    const int l15 = lane & 15, lg = lane >> 4;

    const int ar = tid >> 2, ag = tid & 3;     // staging: row 0..63, k-grp 0..3

    const float* Araw = rawA0
        ? rawA0 + (size_t)yidx[(size_t)(m0 + ar) * TT + t] * lda0 : nullptr;

    f4v accm[2][4], accc[2][4];
    #pragma unroll
    for (int i = 0; i < 2; ++i)
        #pragma unroll
        for (int j = 0; j < 4; ++j) {
            accm[i][j] = (f4v){0.f, 0.f, 0.f, 0.f};
            accc[i][j] = (f4v){0.f, 0.f, 0.f, 0.f};
        }

    uint4 avh, avl, wh0, wl0, wh1, wl1;

    auto load_tile = [&](int kk_) {
        const int col = kk_ + ag * 8;
        if (col < K0) {
            if (Araw) {
                const float4 f0 = *(const float4*)(Araw + col);
                const float4 f1 = *(const float4*)(Araw + col + 4);
                const float xs[8] = {f0.x, f0.y, f0.z, f0.w, f1.x, f1.y, f1.z, f1.w};
                h8v vh, vl;
                #pragma unroll
                for (int j = 0; j < 8; ++j) {
                    _Float16 th, tl;
                    split16(xs[j], th, tl);
                    vh[j] = th;
                    vl[j] = tl;
                }
                avh = *(uint4*)&vh; avl = *(uint4*)&vl;
            } else {
                const size_t o = (size_t)(m0 + ar) * lda0 + col;
                avh = *(const uint4*)(A0h + o);
                avl = *(const uint4*)(A0l + o);
            }
        } else {
            const size_t o = (size_t)(m0 + ar) * lda1 + (col - K0);
            avh = *(const uint4*)(A1h + o);
            avl = *(const uint4*)(A1l + o);
        }
        const size_t o0 = (size_t)(n0 + ar) * Kt + kk_ + ag * 8;
        const size_t o1 = o0 + (size_t)64 * Kt;
        wh0 = *(const uint4*)(Wh + o0);
        wl0 = *(const uint4*)(Wl + o0);
        wh1 = *(const uint4*)(Wh + o1);
        wl1 = *(const uint4*)(Wl + o1);
    };

    load_tile(kbeg);

    for (int kk = kbeg; kk < kend; kk += 32) {
        __syncthreads();

        *(uint4*)&Ash[ar][ag * 8] = avh;
        *(uint4*)&Asl[ar][ag * 8] = avl;
        *(uint4*)&Wsh[ar][ag * 8] = wh0;
        *(uint4*)&Wsl[ar][ag * 8] = wl0;
        *(uint4*)&Wsh[64 + ar][ag * 8] = wh1;
        *(uint4*)&Wsl[64 + ar][ag * 8] = wl1;

        __syncthreads();

        if (kk + 32 < kend) load_tile(kk + 32);   // in flight under compute

        h8v afh[2], afl[2];
        #pragma unroll
        for (int fr = 0; fr < 2; ++fr) {
            const int r = wm * 32 + fr * 16 + l15;
            afh[fr] = *(const h8v*)&Ash[r][lg * 8];
            afl[fr] = *(const h8v*)&Asl[r][lg * 8];
        }
        #pragma unroll
        for (int fn = 0; fn < 4; ++fn) {
            const int r = wn * 64 + fn * 16 + l15;
            const h8v wfh = *(const h8v*)&Wsh[r][lg * 8];
            const h8v wfl = *(const h8v*)&Wsl[r][lg * 8];
            #pragma unroll
            for (int fr = 0; fr < 2; ++fr) {
                accm[fr][fn] = __builtin_amdgcn_mfma_f32_16x16x32_f16(
                    afh[fr], wfh, accm[fr][fn], 0, 0, 0);
                accc[fr][fn] = __builtin_amdgcn_mfma_f32_16x16x32_f16(
                    afh[fr], wfl, accc[fr][fn], 0, 0, 0);
                accc[fr][fn] = __builtin_amdgcn_mfma_f32_16x16x32_f16(
                    afl[fr], wfh, accc[fr][fn], 0, 0, 0);
            }
        }
    }

    const float s12 = 0.000244140625f;  // 2^-12
    float* slab = Cpart + (size_t)p * BB * N;
    #pragma unroll
    for (int fr = 0; fr < 2; ++fr) {
        const int row0 = m0 + wm * 32 + fr * 16 + lg * 4;
        #pragma unroll
        for (int fn = 0; fn < 4; ++fn) {
            const int col = n0 + wn * 64 + fn * 16 + l15;
            #pragma unroll
            for (int j = 0; j < 4; ++j)
                slab[(size_t)(row0 + j) * N + col] =
                    accm[fr][fn][j] + s12 * accc[fr][fn][j];
        }
    }
}

// split-K reduce + bias + tanh; dst and split outputs each optional
__global__ void ep_tanh_s(const float* __restrict__ part, const int P,
                          const float* __restrict__ bias, float* __restrict__ dst,
                          _Float16* __restrict__ dh, _Float16* __restrict__ dl,
                          const int total, const int N)
{
    for (int i = blockIdx.x * blockDim.x + threadIdx.x; i < total;
         i += gridDim.x * blockDim.x) {
        const int n = i % N;
        float s = bias[n];
        for (int p = 0; p < P; ++p) s += part[(size_t)p * total + i];
        const float v = tanhf(s);
        if (dst) dst[i] = v;
        if (dh) split16(v, dh[i], dl[i]);
    }
}

// split-K reduce + biases + LSTM gate pointwise + fp16 split emission
__global__ void ep_gate_s(const float* __restrict__ part, const int P,
                          const float* __restrict__ bih, const float* __restrict__ bhh,
                          float* __restrict__ h, float* __restrict__ c,
                          _Float16* __restrict__ hh, _Float16* __restrict__ hl,
                          _Float16* __restrict__ ch, _Float16* __restrict__ cl)
{
    const int i = blockIdx.x * blockDim.x + threadIdx.x;
    if (i >= BB * HH) return;
    const int b = i >> 10, k = i & (HH - 1);
    const size_t base = (size_t)b * 4 * HH;
    float gi = bih[k] + bhh[k];
    float gf = bih[HH + k] + bhh[HH + k];
    float gg = bih[2 * HH + k] + bhh[2 * HH + k];
    float go = bih[3 * HH + k] + bhh[3 * HH + k];
    for (int p = 0; p < P; ++p) {
        const float* gp = part + (size_t)p * BB * 4 * HH + base;
        gi += gp[k]; gf += gp[HH + k]; gg += gp[2 * HH + k]; go += gp[3 * HH + k];
    }
    const float si = 1.f / (1.f + expf(-gi));
    const float sf = 1.f / (1.f + expf(-gf));
    const float so = 1.f / (1.f + expf(-go));
    const float cn = sf * c[i] + si * tanhf(gg);
    const float hn = so * tanhf(cn);
    c[i] = cn;
    h[i] = hn;
    split16(hn, hh[i], hl[i]);
    if (ch) split16(cn, ch[i], cl[i]);
}

// split-K reduce + bias + logits write + first-max argmax. One block per b.
__global__ __launch_bounds__(256) void ep_argmax(
    const float* __restrict__ part, const int P,
    const float* __restrict__ bias, float* __restrict__ tokens,
    float* __restrict__ logits, const int t)
{
    const int b = blockIdx.x, tid = threadIdx.x;
    __shared__ float vmax[256];
    __shared__ int   vidx[256];

    float best = -INFINITY; int bi = 0;
    #pragma unroll
    for (int j = 0; j < 2; ++j) {
        const int n = tid + j * 256;
        float s = bias[n];
        for (int p = 0; p < P; ++p)
            s += part[(size_t)p * BB * VV + (size_t)b * VV + n];
        logits[((size_t)b * TT + t) * VV + n] = s;
        if (s > best) { best = s; bi = n; }   // ascending n: first-max kept
    }
    vmax[tid] = best; vidx[tid] = bi;
    __syncthreads();
    for (int off = 128; off > 0; off >>= 1) {
        if (tid < off) {
            const float vo = vmax[tid + off]; const int io = vidx[tid + off];
            if (vo > vmax[tid] || (vo == vmax[tid] && io < vidx[tid])) {
                vmax[tid] = vo; vidx[tid] = io;
            }
        }
        __syncthreads();
    }
    if (tid == 0) tokens[(size_t)b * TT + t] = (float)vidx[0];
}

// ===========================================================================
extern "C" void kernel_launch(void* const* d_in, const int* in_sizes, int n_in,
                              void* d_out, int out_size, void* d_ws, size_t ws_size,
                              hipStream_t stream)
{
    const int*   y         = (const int*)  d_in[0];
    const float* enc       = (const float*)d_in[1];
    const float* esum      = (const float*)d_in[2];
    const float* emb_table = (const float*)d_in[3];
    const float* W_init    = (const float*)d_in[4];
    const float* b_init    = (const float*)d_in[5];
    const float* W_ci      = (const float*)d_in[6];
    const float* b_ci      = (const float*)d_in[7];
    const float* Wih0      = (const float*)d_in[8];
    const float* Whh0      = (const float*)d_in[9];
    const float* bih0      = (const float*)d_in[10];
    const float* bhh0      = (const float*)d_in[11];
    const float* Wih1      = (const float*)d_in[12];
    const float* Whh1      = (const float*)d_in[13];
    const float* bih1      = (const float*)d_in[14];
    const float* bhh1      = (const float*)d_in[15];
    const float* Wq        = (const float*)d_in[16];
    const float* bq        = (const float*)d_in[17];
    const float* Wco       = (const float*)d_in[18];
    const float* bco       = (const float*)d_in[19];
    const float* Wout      = (const float*)d_in[20];
    const float* bout      = (const float*)d_in[21];

    float* out    = (float*)d_out;
    float* tokens = out;
    float* logits = out + (size_t)BB * TT;

    // ---- workspace carve ----
    char* wsb = (char*)d_ws;
    size_t off = 0;
    auto alloc = [&](size_t bytes) -> char* {
        char* p = wsb + off;
        off = (off + bytes + 255) & ~(size_t)255;
        return p;
    };
    float* h0    = (float*)alloc((size_t)BB * HH * 4);
    float* h1    = (float*)alloc((size_t)BB * HH * 4);
    float* c0    = (float*)alloc((size_t)BB * HH * 4);
    float* c1    = (float*)alloc((size_t)BB * HH * 4);
    float* cross = (float*)alloc((size_t)BB * ENCE * 4);
    float* xbuf  = (float*)alloc((size_t)BB * EE * 4);
    float* embb  = (float*)alloc((size_t)BB * EE * 4);
    float* gbuf  = (float*)alloc((size_t)BB * 4 * HH * 4);
    float* qbuf  = (float*)alloc((size_t)BB * ENCE * 4);

    float* part = (float*)alloc((size_t)16 * BB * HH * 4);   // 16 MiB

    // fp16 weight splits, row-major [N][ld]
    _Float16 *ci_h, *ci_l, *g0_h, *g0_l, *g1_h, *g1_l, *wq_h, *wq_l,
             *wc_h, *wc_l, *wo_h, *wo_l;
    ci_h = (_Float16*)alloc((size_t)EE * 1536 * 2);
    ci_l = (_Float16*)alloc((size_t)EE * 1536 * 2);
    g0_h = (_Float16*)alloc((size_t)4 * HH * 1536 * 2);
    g0_l = (_Float16*)alloc((size_t)4 * HH * 1536 * 2);
    g1_h = (_Float16*)alloc((size_t)4 * HH * 2048 * 2);
    g1_l = (_Float16*)alloc((size_t)4 * HH * 2048 * 2);
    wq_h = (_Float16*)alloc((size_t)ENCE * 2048 * 2);
    wq_l = (_Float16*)alloc((size_t)ENCE * 2048 * 2);
    wc_h = (_Float16*)alloc((size_t)HH * 2048 * 2);
    wc_l = (_Float16*)alloc((size_t)HH * 2048 * 2);
    wo_h = (_Float16*)alloc((size_t)VV * HH * 2);
    wo_l = (_Float16*)alloc((size_t)VV * HH * 2);

    // fp16 activation splits
    _Float16* xbh  = (_Float16*)alloc((size_t)BB * EE * 2);
    _Float16* xbl  = (_Float16*)alloc((size_t)BB * EE * 2);
    _Float16* h0h  = (_Float16*)alloc((size_t)BB * HH * 2);
    _Float16* h0l  = (_Float16*)alloc((size_t)BB * HH * 2);
    _Float16* h1h  = (_Float16*)alloc((size_t)BB * HH * 2);
    _Float16* h1l  = (_Float16*)alloc((size_t)BB * HH * 2);
    _Float16* c1h  = (_Float16*)alloc((size_t)BB * HH * 2);
    _Float16* c1l  = (_Float16*)alloc((size_t)BB * HH * 2);
    _Float16* crh  = (_Float16*)alloc((size_t)BB * ENCE * 2);
    _Float16* crl  = (_Float16*)alloc((size_t)BB * ENCE * 2);
    _Float16* lnh  = (_Float16*)alloc((size_t)BB * HH * 2);
    _Float16* lnl  = (_Float16*)alloc((size_t)BB * HH * 2);

    // attention partials
    float* po = (float*)alloc((size_t)NSP * BB * ENCE * 4);
    float* pm = (float*)alloc((size_t)NSP * BB * 4);
    float* pl = (float*)alloc((size_t)NSP * BB * 4);
    const size_t need_mfma = off;

    const int mfma_ok = (ws_size >= need_mfma);

    const dim3 thr(256);

    // ---- decoder_init (fp32, once) ----
    gemm2<<<dim3(4 * HH / 64, BB / 64), thr, 0, stream>>>(
        esum, W_init, SUME, SUME, SUME,
        nullptr, nullptr, SUME, 0, 0,
        b_init, nullptr, gbuf, 4 * HH, 1);
    scatter_init_s<<<dim3(BB * 4 * HH / 256), thr, 0, stream>>>(
        gbuf, h0, h1, c0, c1,
        mfma_ok ? h0h : nullptr, h0l, h1h, h1l, c1h, c1l);
    zero_kernel<<<dim3(BB * ENCE / 256), thr, 0, stream>>>(cross, BB * ENCE);

    if (!mfma_ok) {
        for (int t = 0; t < TT; ++t) {
            gather_emb<<<dim3(BB * EE / 256), thr, 0, stream>>>(y, emb_table, embb, t);
            gemm2<<<dim3(EE / 64, BB / 64), thr, 0, stream>>>(
                embb, W_ci, EE, EE, EE + ENCE,
                cross, W_ci + EE, EE + ENCE, ENCE, EE + ENCE,
                b_ci, nullptr, xbuf, EE, 1);
            gemm2<<<dim3(4 * HH / 64, BB / 64), thr, 0, stream>>>(
                xbuf, Wih0, EE, EE, EE,
                h0, Whh0, EE + HH, HH, HH,
                bih0, bhh0, gbuf, 4 * HH, 0);
            lstm_gate<<<dim3(BB * HH / 256), thr, 0, stream>>>(gbuf, h0, c0);
            gemm2<<<dim3(4 * HH / 64, BB / 64), thr, 0, stream>>>(
                h0, Wih1, HH, HH, HH,
                h1, Whh1, 2 * HH, HH, HH,
                bih1, bhh1, gbuf, 4 * HH, 0);
            lstm_gate<<<dim3(BB * HH / 256), thr, 0, stream>>>(gbuf, h1, c1);
            gemm2<<<dim3(ENCE / 64, BB / 64), thr, 0, stream>>>(
                h1, Wq, HH, HH, 2 * HH,
                c1, Wq + HH, 2 * HH, HH, 2 * HH,
                bq, nullptr, qbuf, ENCE, 1);
            attn_kernel<<<dim3(BB), thr, 0, stream>>>(qbuf, enc, cross);
            gemm2<<<dim3(HH / 64, BB / 64), thr, 0, stream>>>(
                h1, Wco, HH, HH, ENCE + HH,
                cross, Wco + HH, ENCE + HH, ENCE, ENCE + HH,
                bco, nullptr, qbuf, HH, 1);
            out_kernel<<<dim3(BB), thr, 0, stream>>>(qbuf, Wout, bout, tokens, logits, t);
        }
        return;
    }

    // ---- one-time weight fp16-splits ----
    const dim3 cg(4096);
    conv_w2<<<cg, thr, 0, stream>>>(W_ci, EE, EE + ENCE, ci_h, ci_l, 1536, 0);
    conv_w2<<<cg, thr, 0, stream>>>(Wih0, 4 * HH, EE, g0_h, g0_l, 1536, 0);
    conv_w2<<<cg, thr, 0, stream>>>(Whh0, 4 * HH, HH, g0_h, g0_l, 1536, EE);
    conv_w2<<<cg, thr, 0, stream>>>(Wih1, 4 * HH, HH, g1_h, g1_l, 2048, 0);
    conv_w2<<<cg, thr, 0, stream>>>(Whh1, 4 * HH, HH, g1_h, g1_l, 2048, HH);
    conv_w2<<<cg, thr, 0, stream>>>(Wq, ENCE, 2 * HH, wq_h, wq_l, 2048, 0);
    conv_w2<<<cg, thr, 0, stream>>>(Wco, HH, ENCE + HH, wc_h, wc_l, 2048, 0);
    conv_w2<<<cg, thr, 0, stream>>>(Wout, VV, HH, wo_h, wo_l, HH, 0);
    // cross = 0 at t=0 (fp16 zero == bits zero)
    zero_kernel<<<dim3(BB * ENCE / 512), thr, 0, stream>>>((float*)crh, BB * ENCE / 2);
    zero_kernel<<<dim3(BB * ENCE / 512), thr, 0, stream>>>((float*)crl, BB * ENCE / 2);

    auto gemmS = [&](const _Float16* a0h, const _Float16* a0l, int lda0,
                     const _Float16* a1h, const _Float16* a1l, int lda1, int K0,
                     const float* raw0, const int* yi, int t_,
                     const _Float16* wh, const _Float16* wl,
                     int Kt, int N, int P) {
        gemm_f16<<<dim3(N / 128, BB / 64, P), thr, 0, stream>>>(
            a0h, a0l, lda0, a1h, a1l, lda1, K0, raw0, yi, t_,
            wh, wl, Kt, part, N, Kt / P);
    };

    for (int t = 0; t < TT; ++t) {
        // x = tanh([emb_table[y[:,t]] | cross] @ Wci^T + b_ci)  (fused gather)
        gemmS(nullptr, nullptr, EE, crh, crl, ENCE, EE,
              emb_table, y, t, ci_h, ci_l, 1536, EE, 8);
        ep_tanh_s<<<dim3(512), thr, 0, stream>>>(part, 8, b_ci, nullptr, xbh, xbl,
                                                 BB * EE, EE);

        // layer0 gates
        gemmS(xbh, xbl, EE, h0h, h0l, HH, EE, nullptr, nullptr, 0,
              g0_h, g0_l, 1536, 4 * HH, 4);
        ep_gate_s<<<dim3(BB * HH / 256), thr, 0, stream>>>(
            part, 4, bih0, bhh0, h0, c0, h0h, h0l, nullptr, nullptr);

        // layer1 gates
        gemmS(h0h, h0l, HH, h1h, h1l, HH, HH, nullptr, nullptr, 0,
              g1_h, g1_l, 2048, 4 * HH, 4);
        ep_gate_s<<<dim3(BB * HH / 256), thr, 0, stream>>>(
            part, 4, bih1, bhh1, h1, c1, h1h, h1l, c1h, c1l);

        // q = tanh([h1 | c1] @ Wq^T + bq)  (fp32 q for attention)
        gemmS(h1h, h1l, HH, c1h, c1l, HH, HH, nullptr, nullptr, 0,
              wq_h, wq_l, 2048, ENCE, 8);
        ep_tanh_s<<<dim3(1024), thr, 0, stream>>>(part, 8, bq, qbuf, nullptr, nullptr,
                                                  BB * ENCE, ENCE);

        // attention: split-flash partials + combine -> cross splits
        attn_part_k<<<dim3(NSP, BB), thr, 0, stream>>>(qbuf, enc, po, pm, pl);
        attn_comb_k<<<dim3(BB), thr, 0, stream>>>(po, pm, pl, crh, crl);

        // lin = tanh([h1 | cross] @ Wco^T + bco) -> splits only
        gemmS(h1h, h1l, HH, crh, crl, ENCE, HH, nullptr, nullptr, 0,
              wc_h, wc_l, 2048, HH, 8);
        ep_tanh_s<<<dim3(1024), thr, 0, stream>>>(part, 8, bco, nullptr, lnh, lnl,
                                                  BB * HH, HH);

        // logits GEMM + fused argmax epilogue
        gemmS(lnh, lnl, HH, nullptr, nullptr, HH, HH, nullptr, nullptr, 0,
              wo_h, wo_l, HH, VV, 8);
        ep_argmax<<<dim3(BB), thr, 0, stream>>>(part, 8, bout, tokens, logits, t);
    }
}